// Round 1
// 969.079 us; speedup vs baseline: 1.1070x; 1.1070x over previous
//
#include <hip/hip_runtime.h>

#define D_MODEL 1024
#define NH 16
#define DK 64
#define DFF 4096
#define SEQ 2048
#define BATCH 4
#define NROWS (BATCH*SEQ)   // 8192
#define CHUNK 2048          // FFN row-chunk (16MB bf16 hidden fits dead k region)
#define NCHUNK (NROWS/CHUNK)

typedef short bf16x8 __attribute__((ext_vector_type(8)));
typedef float f32x4 __attribute__((ext_vector_type(4)));

__device__ __forceinline__ float bf2f(unsigned short u){
  union { float f; unsigned int i; } x; x.i = ((unsigned int)u) << 16; return x.f;
}
__device__ __forceinline__ unsigned short f2bf(float f){
  union { float f; unsigned int i; } x; x.f = f;
  unsigned int r = x.i + 0x7fffu + ((x.i >> 16) & 1u);
  return (unsigned short)(r >> 16);
}

// async global->LDS, 16B per lane (m97 pattern; LDS dest = wave base + lane*16)
__device__ __forceinline__ void gl_lds16(const void* g, void* l) {
  __builtin_amdgcn_global_load_lds((const __attribute__((address_space(1))) void*)g,
                                   (__attribute__((address_space(3))) void*)l, 16, 0, 0);
}

// ---------------- fp32 -> bf16 bulk convert (weights) ----------------
__global__ __launch_bounds__(256) void cvt_f2b(const float* __restrict__ in,
                                               unsigned short* __restrict__ out, int n)
{
  int i = (blockIdx.x * 256 + threadIdx.x) * 4;
  if (i < n) {
    float4 f = *(const float4*)(in + i);
    union { int2 v; unsigned short u[4]; } o;
    o.u[0] = f2bf(f.x); o.u[1] = f2bf(f.y); o.u[2] = f2bf(f.z); o.u[3] = f2bf(f.w);
    *(int2*)(out + i) = o.v;
  }
}

// ---------------- LayerNorm: fp32 in -> bf16 out, one block per row of 1024 ----
// torch variant: unbiased std (ddof=1), eps added to std (not var)
__global__ __launch_bounds__(256) void ln_kernel(const float* __restrict__ in,
    const float* __restrict__ gam, const float* __restrict__ bet,
    unsigned short* __restrict__ out)
{
  const int row = blockIdx.x, t = threadIdx.x;
  const int base = t * 4;
  float4 raw = *(const float4*)(in + (size_t)row * D_MODEL + base);
  float v[4] = { raw.x, raw.y, raw.z, raw.w };
  float s  = v[0] + v[1] + v[2] + v[3];
  float s2 = v[0]*v[0] + v[1]*v[1] + v[2]*v[2] + v[3]*v[3];
  #pragma unroll
  for (int off = 32; off > 0; off >>= 1) {
    s  += __shfl_down(s,  off);
    s2 += __shfl_down(s2, off);
  }
  __shared__ float red[10];
  const int wid = t >> 6, lane = t & 63;
  if (lane == 0) { red[wid] = s; red[4 + wid] = s2; }
  __syncthreads();
  if (t == 0) {
    float ts  = red[0] + red[1] + red[2] + red[3];
    float ts2 = red[4] + red[5] + red[6] + red[7];
    float mean = ts * (1.0f / D_MODEL);
    float var  = (ts2 - (float)D_MODEL * mean * mean) * (1.0f / (D_MODEL - 1));
    var = fmaxf(var, 0.0f);
    red[8] = mean;
    red[9] = 1.0f / (sqrtf(var) + 1e-6f);
  }
  __syncthreads();
  const float mean = red[8], inv = red[9];
  float4 g4 = *(const float4*)(gam + base);
  float4 b4 = *(const float4*)(bet + base);
  union { int2 v; unsigned short u[4]; } o;
  o.u[0] = f2bf(g4.x * (v[0] - mean) * inv + b4.x);
  o.u[1] = f2bf(g4.y * (v[1] - mean) * inv + b4.y);
  o.u[2] = f2bf(g4.z * (v[2] - mean) * inv + b4.z);
  o.u[3] = f2bf(g4.w * (v[3] - mean) * inv + b4.w);
  *(int2*)(out + (size_t)row * D_MODEL + base) = o.v;
}

// ---------------- GEMM: C[m,n] = sum_k A[m,k] * Bw[n,k]  (+ epilogue) ----------
// All-bf16 operands; global_load_lds width-16 staging (m97 pattern).
// 128x128 tile, BK=32, 4 waves (2x2), each wave 64x64 via 4x4 mfma_16x16x32_bf16.
// QKV mode (outq!=null): N=3072 fused; col block 0->q, 1->k, 2->vt (transposed).
__global__ __launch_bounds__(256) void gemm_bt(
    const unsigned short* __restrict__ A,   // [M,K] bf16
    const unsigned short* __restrict__ Bw,  // [N,K] bf16
    int K, int N,
    const float* __restrict__ bias,    // [N] fp32 or null
    int relu,
    const float* __restrict__ residf,  // [M,N] fp32 or null
    unsigned short* __restrict__ outb, // [M,N] bf16 or null
    float* __restrict__ outf,          // [M,N] fp32 or null
    unsigned short* __restrict__ outq, // fused-QKV q  [M,1024] or null
    unsigned short* __restrict__ outk, //           k  [M,1024]
    unsigned short* __restrict__ outvt)//           v^T [(b,h),d,s]
{
  __shared__ __attribute__((aligned(16))) short sA[128 * 32];
  __shared__ __attribute__((aligned(16))) short sB[128 * 32];
  const int t = threadIdx.x;
  const int tileN = blockIdx.x * 128;
  const int tileM = blockIdx.y * 128;
  const int wid = t >> 6, lane = t & 63;
  const int wM = (wid >> 1) * 64, wN = (wid & 1) * 64;
  const int quad = lane >> 4, lrow = lane & 15;

  f32x4 acc[4][4] = {};

  for (int k0 = 0; k0 < K; k0 += 32) {
    #pragma unroll
    for (int it = 0; it < 2; it++) {
      int seg = it * 256 + t;            // 512 x 16B segments per 8KB tile
      int row = seg >> 2, c8 = (seg & 3) * 8;
      gl_lds16(A  + (size_t)(tileM + row) * K + k0 + c8, &sA[seg * 8]);
      gl_lds16(Bw + (size_t)(tileN + row) * K + k0 + c8, &sB[seg * 8]);
    }
    __syncthreads();
    bf16x8 af[4], bfr[4];
    #pragma unroll
    for (int i = 0; i < 4; i++) {
      af[i]  = *(const bf16x8*)&sA[(wM + i * 16 + lrow) * 32 + quad * 8];
      bfr[i] = *(const bf16x8*)&sB[(wN + i * 16 + lrow) * 32 + quad * 8];
    }
    #pragma unroll
    for (int i = 0; i < 4; i++)
      #pragma unroll
      for (int j = 0; j < 4; j++)
        acc[i][j] = __builtin_amdgcn_mfma_f32_16x16x32_bf16(af[i], bfr[j], acc[i][j], 0, 0, 0);
    __syncthreads();
  }

  // fused-QKV epilogue target for this block (tileN is 128-aligned; one cat/block)
  unsigned short* qk_out = nullptr;
  int qkv_cat = 0;
  if (outq) {
    qkv_cat = tileN >> 10;                 // 0=q 1=k 2=v
    qk_out = (qkv_cat == 0) ? outq : outk;
  }

  #pragma unroll
  for (int i = 0; i < 4; i++) {
    #pragma unroll
    for (int j = 0; j < 4; j++) {
      const int col  = tileN + wN + j * 16 + lrow;
      const int row0 = tileM + wM + i * 16 + quad * 4;
      const float bv = bias ? bias[col] : 0.0f;
      float vals[4];
      #pragma unroll
      for (int r = 0; r < 4; r++) {
        float val = acc[i][j][r] + bv;
        if (relu) val = fmaxf(val, 0.0f);
        if (residf) val += residf[(size_t)(row0 + r) * N + col];
        vals[r] = val;
      }
      if (outq) {
        const int lcol = col & 1023;
        if (qkv_cat < 2) {
          #pragma unroll
          for (int r = 0; r < 4; r++)
            qk_out[(size_t)(row0 + r) * D_MODEL + lcol] = f2bf(vals[r]);
        } else {
          // vt[((b*NH+h)*DK+d)*SEQ + s]: b=row>>11, s=row&2047, h=lcol>>6, d=lcol&63
          union { int2 v; unsigned short u[4]; } pk;
          #pragma unroll
          for (int r = 0; r < 4; r++) pk.u[r] = f2bf(vals[r]);
          size_t tidx = (((size_t)(row0 >> 11) * NH + (lcol >> 6)) * DK + (lcol & 63)) * SEQ + (row0 & 2047);
          *(int2*)(outvt + tidx) = pk.v;
        }
      } else {
        #pragma unroll
        for (int r = 0; r < 4; r++) {
          const size_t idx = (size_t)(row0 + r) * N + col;
          if (outf) outf[idx] = vals[r];
          if (outb) outb[idx] = f2bf(vals[r]);
        }
      }
    }
  }
}

// ---------------- MFMA flash attention (v2: swapped QK^T, lane-local softmax) --
// Block = 4 waves, 64 Q-rows of one (b,h). KV tiles of 64. Online softmax.
// QK^T computed as mfma(K,Q) so each lane owns ONE q-column (q = wv*16+l15) with
// kv in the register dim: row max/sum are lane-local + 2 shfl_xor (vs 32 shfls),
// m/l/alpha are scalars (1 exp vs 4). P written packed (ds_write_b64, cvt_pk).
// LDS tiles are [64][64] shorts with XOR swizzle col^=(row&7)<<3 (16B granules):
// conflict-free for staging writes, K/V/P b128 reads, and P b64 writes.
// K/V staged via global_load_lds with PRE-SWIZZLED global source (m173 pattern).
// Og may alias Qg (Q frags register-resident before any write).
#define AQT 64
#define AKT 64
__global__ __launch_bounds__(256) void attn_mfma(
    const unsigned short* __restrict__ Qg,   // [B*S][D_MODEL] bf16
    const unsigned short* __restrict__ Kg,   // [B*S][D_MODEL] bf16
    const unsigned short* __restrict__ Vt,   // [(b*NH+h)*DK + d][SEQ] bf16 (transposed)
    const int* __restrict__ mask,            // [B*S]
    unsigned short* __restrict__ Og)
{
  __shared__ __attribute__((aligned(16))) short Ks[AKT * 64];
  __shared__ __attribute__((aligned(16))) short Vs[DK * 64];
  __shared__ __attribute__((aligned(16))) short Ps[AQT * 64];
  __shared__ __attribute__((aligned(16))) float maddf[AKT];

  const int bid = blockIdx.x;
  const int nqt = SEQ / AQT;          // 32
  const int b  = bid / (NH * nqt);
  const int h  = (bid / nqt) % NH;
  const int q0 = (bid % nqt) * AQT;
  const int t  = threadIdx.x;
  const int wv = t >> 6, lane = t & 63;
  const int quad = lane >> 4, l15 = lane & 15;
  const int sw = (l15 & 7) << 3;      // shared XOR swizzle for all row&7==l15&7 reads

  bf16x8 qf0, qf1;
  {
    const unsigned short* qrow = Qg + (size_t)(b * SEQ + q0 + wv * 16 + l15) * D_MODEL + h * DK;
    qf0 = *(const bf16x8*)(qrow + quad * 8);
    qf1 = *(const bf16x8*)(qrow + 32 + quad * 8);
  }
  f32x4 oacc[4] = {};
  float m_run = -1e30f, l_run = 0.0f;

  const unsigned short* Kbase = Kg + (size_t)(b * SEQ) * D_MODEL + h * DK;
  const unsigned short* Vbase = Vt + ((size_t)(b * NH + h) * DK) * SEQ;

  for (int kt = 0; kt < SEQ; kt += AKT) {
    // stage K,V tiles: 512 x 16B segments each; LDS linear, global col pre-swizzled
    #pragma unroll
    for (int it = 0; it < 2; it++) {
      int s = it * 256 + t;
      int row = s >> 3;
      int scol = ((s & 7) * 8) ^ ((row & 7) << 3);
      gl_lds16(Kbase + (size_t)(kt + row) * D_MODEL + scol, &Ks[s * 8]);
      gl_lds16(Vbase + (size_t)row * SEQ + kt + scol, &Vs[s * 8]);
    }
    if (t < AKT) maddf[t] = mask[b * SEQ + kt + t] ? 0.0f : -1e9f;
    __syncthreads();

    // swapped QK^T: out[m=kv=ct*16+quad*4+r][n=q=l15]
    f32x4 sc[4];
    #pragma unroll
    for (int ct = 0; ct < 4; ct++) {
      const int krow = ct * 16 + l15;
      bf16x8 kb0 = *(const bf16x8*)&Ks[krow * 64 + ((quad * 8) ^ sw)];
      bf16x8 kb1 = *(const bf16x8*)&Ks[krow * 64 + ((32 + quad * 8) ^ sw)];
      f32x4 a = {};
      a = __builtin_amdgcn_mfma_f32_16x16x32_bf16(kb0, qf0, a, 0, 0, 0);
      a = __builtin_amdgcn_mfma_f32_16x16x32_bf16(kb1, qf1, a, 0, 0, 0);
      f32x4 md = *(const f32x4*)&maddf[ct * 16 + quad * 4];
      #pragma unroll
      for (int r = 0; r < 4; r++) a[r] = a[r] * 0.125f + md[r];
      sc[ct] = a;
    }

    // lane-local row max over 16 kv values, then combine the 4 quads
    float tmax = sc[0][0];
    #pragma unroll
    for (int ct = 0; ct < 4; ct++)
      #pragma unroll
      for (int r = 0; r < 4; r++) tmax = fmaxf(tmax, sc[ct][r]);
    tmax = fmaxf(tmax, __shfl_xor(tmax, 16));
    tmax = fmaxf(tmax, __shfl_xor(tmax, 32));

    // defer-max (T13): only rescale when max grew by > 8 (wave-uniform branch)
    if (!__all(tmax - m_run <= 8.0f)) {
      float mn = fmaxf(m_run, tmax);
      float alpha = __expf(m_run - mn);
      m_run = mn;
      l_run *= alpha;
      float a4[4];
      #pragma unroll
      for (int r = 0; r < 4; r++) a4[r] = __shfl(alpha, quad * 4 + r);
      #pragma unroll
      for (int dt = 0; dt < 4; dt++)
        #pragma unroll
        for (int r = 0; r < 4; r++) oacc[dt][r] *= a4[r];
    }

    // P = exp(S - m); packed bf16 store: 4x ds_write_b64 (P[q][kv] layout, swizzled)
    const int prow = wv * 16 + l15;
    float rs = 0.0f;
    #pragma unroll
    for (int ct = 0; ct < 4; ct++) {
      float p0 = __expf(sc[ct][0] - m_run);
      float p1 = __expf(sc[ct][1] - m_run);
      float p2 = __expf(sc[ct][2] - m_run);
      float p3 = __expf(sc[ct][3] - m_run);
      rs += (p0 + p1) + (p2 + p3);
      unsigned int lo, hi;
      asm("v_cvt_pk_bf16_f32 %0, %1, %2" : "=v"(lo) : "v"(p0), "v"(p1));
      asm("v_cvt_pk_bf16_f32 %0, %1, %2" : "=v"(hi) : "v"(p2), "v"(p3));
      int2 pv; pv.x = (int)lo; pv.y = (int)hi;
      *(int2*)&Ps[prow * 64 + ((ct * 16 + quad * 4) ^ sw)] = pv;
    }
    rs += __shfl_xor(rs, 16);
    rs += __shfl_xor(rs, 32);
    l_run += rs;

    // PV: A = P[q][kv 8-contig] (own wave's rows), B = V[kv][d] from Vs[d][kv]
    bf16x8 pf0 = *(const bf16x8*)&Ps[prow * 64 + ((quad * 8) ^ sw)];
    bf16x8 pf1 = *(const bf16x8*)&Ps[prow * 64 + ((32 + quad * 8) ^ sw)];
    #pragma unroll
    for (int dt = 0; dt < 4; dt++) {
      const int vrow = dt * 16 + l15;
      bf16x8 vb0 = *(const bf16x8*)&Vs[vrow * 64 + ((quad * 8) ^ sw)];
      bf16x8 vb1 = *(const bf16x8*)&Vs[vrow * 64 + ((32 + quad * 8) ^ sw)];
      oacc[dt] = __builtin_amdgcn_mfma_f32_16x16x32_bf16(pf0, vb0, oacc[dt], 0, 0, 0);
      oacc[dt] = __builtin_amdgcn_mfma_f32_16x16x32_bf16(pf1, vb1, oacc[dt], 0, 0, 0);
    }
    __syncthreads();
  }

  // transport 1/l from lane-layout (q=l15) to C-layout (q=quad*4+r)
  float li = 1.0f / l_run;
  float linv4[4];
  #pragma unroll
  for (int r = 0; r < 4; r++) linv4[r] = __shfl(li, quad * 4 + r);
  #pragma unroll
  for (int dt = 0; dt < 4; dt++)
    #pragma unroll
    for (int r = 0; r < 4; r++)
      Og[(size_t)(b * SEQ + q0 + wv * 16 + quad * 4 + r) * D_MODEL + h * DK + dt * 16 + l15] =
        f2bf(oacc[dt][r] * linv4[r]);
}

// ---------------- launch ----------------
// fp32 I/O. All GEMMs bf16 with just-in-time weight conversion. NO ws_size gate.
// ws high-water 48MB:
//   phase A: q [0,16)  k [16,32)  vt [32,48)
//   phase B (after attn): ao=q, wo16 -> [16,18) (k dead)
//   phase C (after o-proj): w1 -> [0,8), w2 -> [8,16) (ao dead); ln2 -> [32,48)
//            hff chunk -> [16,32)
// d_out as scratch: ln1b [0,16MB), wqkv16 [16,22MB); o-proj overwrites all with x1 fp32.
extern "C" void kernel_launch(void* const* d_in, const int* in_sizes, int n_in,
                              void* d_out, int out_size, void* d_ws, size_t ws_size,
                              hipStream_t stream)
{
  (void)in_sizes; (void)n_in; (void)out_size; (void)ws_size;
  const float* x   = (const float*)d_in[0];
  const int*   msk = (const int*)d_in[1];
  const float* w_q = (const float*)d_in[2];
  const float* w_k = (const float*)d_in[3];
  const float* w_v = (const float*)d_in[4];
  const float* w_o = (const float*)d_in[5];
  const float* w1  = (const float*)d_in[6];
  const float* b1  = (const float*)d_in[7];
  const float* w2  = (const float*)d_in[8];
  const float* b2  = (const float*)d_in[9];
  const float* g1  = (const float*)d_in[10];
  const float* be1 = (const float*)d_in[11];
  const float* g2  = (const float*)d_in[12];
  const float* be2 = (const float*)d_in[13];
  float* outf = (float*)d_out;

  char* ws = (char*)d_ws;
  const size_t MB = 1024 * 1024;
  unsigned short* q_b  = (unsigned short*)(ws + 0);        // 16MB -> ao
  unsigned short* k_b  = (unsigned short*)(ws + 16 * MB);  // 16MB -> wo16 -> hff chunk
  unsigned short* vt_b = (unsigned short*)(ws + 32 * MB);  // 16MB -> ln2b
  unsigned short* wo16 = (unsigned short*)(ws + 16 * MB);  // 2MB (k dead after attn)
  unsigned short* w116 = (unsigned short*)(ws + 0);        // 8MB (ao dead after o-proj)
  unsigned short* w216 = (unsigned short*)(ws + 8 * MB);   // 8MB
  unsigned short* ln2b = vt_b;                             // 16MB (vt dead after attn)
  unsigned short* hffc = k_b;                              // 16MB chunk

  unsigned short* ln1b   = (unsigned short*)d_out;                  // [0,16MB) of d_out
  unsigned short* wqkv16 = (unsigned short*)d_out + 8 * 1024 * 1024;// [16,22MB) of d_out

  dim3 blk(256);
  const int nw = D_MODEL * D_MODEL;  // 1M elems
  const int nf = DFF * D_MODEL;      // 4M elems

  // phase A: weights q|k|v -> fused bf16 [3072,1024] in d_out scratch; LN1
  cvt_f2b<<<nw / 1024, blk, 0, stream>>>(w_q, wqkv16, nw);
  cvt_f2b<<<nw / 1024, blk, 0, stream>>>(w_k, wqkv16 + nw, nw);
  cvt_f2b<<<nw / 1024, blk, 0, stream>>>(w_v, wqkv16 + 2 * nw, nw);
  ln_kernel<<<NROWS, blk, 0, stream>>>(x, g1, be1, ln1b);

  // fused QKV: [8192,1024] x [3072,1024]^T -> q, k, vt
  dim3 gqkv(3 * D_MODEL / 128, NROWS / 128);  // (24, 64) = 1536 blocks
  gemm_bt<<<gqkv, blk, 0, stream>>>(ln1b, wqkv16, D_MODEL, 3 * D_MODEL, nullptr, 0,
                                    nullptr, nullptr, nullptr, q_b, k_b, vt_b);

  // attention (output in-place over q)
  attn_mfma<<<BATCH * NH * (SEQ / AQT), blk, 0, stream>>>(q_b, k_b, vt_b, msk, q_b);

  // phase B: wo -> dead k region; o-proj + residual(x) -> x1 = d_out (fp32)
  cvt_f2b<<<nw / 1024, blk, 0, stream>>>(w_o, wo16, nw);
  dim3 gN1024(D_MODEL / 128, NROWS / 128);  // (8, 64)
  gemm_bt<<<gN1024, blk, 0, stream>>>(q_b, wo16, D_MODEL, D_MODEL, nullptr, 0, x,
                                      nullptr, outf, nullptr, nullptr, nullptr);

  // phase C: w1/w2 -> dead ao region; LN2 -> dead vt region; chunked FFN
  cvt_f2b<<<nf / 1024, blk, 0, stream>>>(w1, w116, nf);
  cvt_f2b<<<nf / 1024, blk, 0, stream>>>(w2, w216, nf);
  ln_kernel<<<NROWS, blk, 0, stream>>>(outf, g2, be2, ln2b);
  for (int c = 0; c < NCHUNK; c++) {
    const size_t ro = (size_t)c * CHUNK;
    dim3 g1c(DFF / 128,     CHUNK / 128);   // (32, 16)
    dim3 g2c(D_MODEL / 128, CHUNK / 128);   // (8, 16)
    gemm_bt<<<g1c, blk, 0, stream>>>(ln2b + ro * D_MODEL, w116, D_MODEL, DFF, b1, 1,
                                     nullptr, hffc, nullptr, nullptr, nullptr, nullptr);
    gemm_bt<<<g2c, blk, 0, stream>>>(hffc, w216, DFF, D_MODEL, b2, 0,
                                     outf + ro * D_MODEL, nullptr, outf + ro * D_MODEL,
                                     nullptr, nullptr, nullptr);
  }
}

// Round 2
// 774.254 us; speedup vs baseline: 1.3856x; 1.2516x over previous
//
#include <hip/hip_runtime.h>

#define D_MODEL 1024
#define NH 16
#define DK 64
#define DFF 4096
#define SEQ 2048
#define BATCH 4
#define NROWS (BATCH*SEQ)   // 8192
#define CHUNK 2048          // FFN row-chunk (16MB bf16 hidden fits dead k region)
#define NCHUNK (NROWS/CHUNK)

typedef short bf16x8 __attribute__((ext_vector_type(8)));
typedef float f32x4 __attribute__((ext_vector_type(4)));

__device__ __forceinline__ float bf2f(unsigned short u){
  union { float f; unsigned int i; } x; x.i = ((unsigned int)u) << 16; return x.f;
}
__device__ __forceinline__ unsigned short f2bf(float f){
  union { float f; unsigned int i; } x; x.f = f;
  unsigned int r = x.i + 0x7fffu + ((x.i >> 16) & 1u);
  return (unsigned short)(r >> 16);
}
__device__ __forceinline__ float fexp2(float x){
#if __has_builtin(__builtin_amdgcn_exp2f)
  return __builtin_amdgcn_exp2f(x);
#else
  return __exp2f(x);
#endif
}

// async global->LDS, 16B per lane (m97 pattern; LDS dest = wave base + lane*16)
__device__ __forceinline__ void gl_lds16(const void* g, void* l) {
  __builtin_amdgcn_global_load_lds((const __attribute__((address_space(1))) void*)g,
                                   (__attribute__((address_space(3))) void*)l, 16, 0, 0);
}

// ---------------- fp32 -> bf16 bulk convert (weights) ----------------
__global__ __launch_bounds__(256) void cvt_f2b(const float* __restrict__ in,
                                               unsigned short* __restrict__ out, int n)
{
  int i = (blockIdx.x * 256 + threadIdx.x) * 4;
  if (i < n) {
    float4 f = *(const float4*)(in + i);
    union { int2 v; unsigned short u[4]; } o;
    o.u[0] = f2bf(f.x); o.u[1] = f2bf(f.y); o.u[2] = f2bf(f.z); o.u[3] = f2bf(f.w);
    *(int2*)(out + i) = o.v;
  }
}

// ---------------- LayerNorm: fp32 in -> bf16 out, one block per row of 1024 ----
// torch variant: unbiased std (ddof=1), eps added to std (not var)
__global__ __launch_bounds__(256) void ln_kernel(const float* __restrict__ in,
    const float* __restrict__ gam, const float* __restrict__ bet,
    unsigned short* __restrict__ out)
{
  const int row = blockIdx.x, t = threadIdx.x;
  const int base = t * 4;
  float4 raw = *(const float4*)(in + (size_t)row * D_MODEL + base);
  float v[4] = { raw.x, raw.y, raw.z, raw.w };
  float s  = v[0] + v[1] + v[2] + v[3];
  float s2 = v[0]*v[0] + v[1]*v[1] + v[2]*v[2] + v[3]*v[3];
  #pragma unroll
  for (int off = 32; off > 0; off >>= 1) {
    s  += __shfl_down(s,  off);
    s2 += __shfl_down(s2, off);
  }
  __shared__ float red[10];
  const int wid = t >> 6, lane = t & 63;
  if (lane == 0) { red[wid] = s; red[4 + wid] = s2; }
  __syncthreads();
  if (t == 0) {
    float ts  = red[0] + red[1] + red[2] + red[3];
    float ts2 = red[4] + red[5] + red[6] + red[7];
    float mean = ts * (1.0f / D_MODEL);
    float var  = (ts2 - (float)D_MODEL * mean * mean) * (1.0f / (D_MODEL - 1));
    var = fmaxf(var, 0.0f);
    red[8] = mean;
    red[9] = 1.0f / (sqrtf(var) + 1e-6f);
  }
  __syncthreads();
  const float mean = red[8], inv = red[9];
  float4 g4 = *(const float4*)(gam + base);
  float4 b4 = *(const float4*)(bet + base);
  union { int2 v; unsigned short u[4]; } o;
  o.u[0] = f2bf(g4.x * (v[0] - mean) * inv + b4.x);
  o.u[1] = f2bf(g4.y * (v[1] - mean) * inv + b4.y);
  o.u[2] = f2bf(g4.z * (v[2] - mean) * inv + b4.z);
  o.u[3] = f2bf(g4.w * (v[3] - mean) * inv + b4.w);
  *(int2*)(out + (size_t)row * D_MODEL + base) = o.v;
}

// ---------------- GEMM: C[m,n] = sum_k A[m,k] * Bw[n,k]  (+ epilogue) ----------
// All-bf16 operands; global_load_lds width-16 staging (m97 pattern).
// 128x128 tile, BK=32, 4 waves (2x2), each wave 64x64 via 4x4 mfma_16x16x32_bf16.
// QKV mode (outq!=null): N=3072 fused; col block 0->q, 1->k, 2->vt (transposed).
// Split-K mode (atomf!=null): grid.z = #splits, each handles K cols
//   [z*K, (z+1)*K) of rows with stride sA/sB; epilogue atomicAdd fp32
//   (bias added by z==0 only). Target must be pre-initialized (residual).
__global__ __launch_bounds__(256) void gemm_bt(
    const unsigned short* __restrict__ A,   // [M,*] bf16, row stride sA
    const unsigned short* __restrict__ Bw,  // [N,*] bf16, row stride sB
    int K, int N, int sA, int sB,
    const float* __restrict__ bias,    // [N] fp32 or null
    int relu,
    const float* __restrict__ residf,  // [M,N] fp32 or null
    unsigned short* __restrict__ outb, // [M,N] bf16 or null
    float* __restrict__ outf,          // [M,N] fp32 or null
    float* __restrict__ atomf,         // [M,N] fp32 atomic-accum or null
    unsigned short* __restrict__ outq, // fused-QKV q  [M,1024] or null
    unsigned short* __restrict__ outk, //           k  [M,1024]
    unsigned short* __restrict__ outvt)//           v^T [(b,h),d,s]
{
  __shared__ __attribute__((aligned(16))) short sAm[128 * 32];
  __shared__ __attribute__((aligned(16))) short sBm[128 * 32];
  const int t = threadIdx.x;
  const int tileN = blockIdx.x * 128;
  const int tileM = blockIdx.y * 128;
  const int kz = blockIdx.z;
  const size_t koff = (size_t)kz * K;
  const int wid = t >> 6, lane = t & 63;
  const int wM = (wid >> 1) * 64, wN = (wid & 1) * 64;
  const int quad = lane >> 4, lrow = lane & 15;

  f32x4 acc[4][4] = {};

  for (int k0 = 0; k0 < K; k0 += 32) {
    #pragma unroll
    for (int it = 0; it < 2; it++) {
      int seg = it * 256 + t;            // 512 x 16B segments per 8KB tile
      int row = seg >> 2, c8 = (seg & 3) * 8;
      gl_lds16(A  + (size_t)(tileM + row) * sA + koff + k0 + c8, &sAm[seg * 8]);
      gl_lds16(Bw + (size_t)(tileN + row) * sB + koff + k0 + c8, &sBm[seg * 8]);
    }
    __syncthreads();
    bf16x8 af[4], bfr[4];
    #pragma unroll
    for (int i = 0; i < 4; i++) {
      af[i]  = *(const bf16x8*)&sAm[(wM + i * 16 + lrow) * 32 + quad * 8];
      bfr[i] = *(const bf16x8*)&sBm[(wN + i * 16 + lrow) * 32 + quad * 8];
    }
    #pragma unroll
    for (int i = 0; i < 4; i++)
      #pragma unroll
      for (int j = 0; j < 4; j++)
        acc[i][j] = __builtin_amdgcn_mfma_f32_16x16x32_bf16(af[i], bfr[j], acc[i][j], 0, 0, 0);
    __syncthreads();
  }

  // fused-QKV epilogue target for this block (tileN is 128-aligned; one cat/block)
  unsigned short* qk_out = nullptr;
  int qkv_cat = 0;
  if (outq) {
    qkv_cat = tileN >> 10;                 // 0=q 1=k 2=v
    qk_out = (qkv_cat == 0) ? outq : outk;
  }

  #pragma unroll
  for (int i = 0; i < 4; i++) {
    #pragma unroll
    for (int j = 0; j < 4; j++) {
      const int col  = tileN + wN + j * 16 + lrow;
      const int row0 = tileM + wM + i * 16 + quad * 4;
      const float bv = (bias && kz == 0) ? bias[col] : 0.0f;
      float vals[4];
      #pragma unroll
      for (int r = 0; r < 4; r++) {
        float val = acc[i][j][r] + bv;
        if (relu) val = fmaxf(val, 0.0f);
        if (residf) val += residf[(size_t)(row0 + r) * N + col];
        vals[r] = val;
      }
      if (outq) {
        const int lcol = col & 1023;
        if (qkv_cat < 2) {
          #pragma unroll
          for (int r = 0; r < 4; r++)
            qk_out[(size_t)(row0 + r) * D_MODEL + lcol] = f2bf(vals[r]);
        } else {
          // vt[((b*NH+h)*DK+d)*SEQ + s]: b=row>>11, s=row&2047, h=lcol>>6, d=lcol&63
          union { int2 v; unsigned short u[4]; } pk;
          #pragma unroll
          for (int r = 0; r < 4; r++) pk.u[r] = f2bf(vals[r]);
          size_t tidx = (((size_t)(row0 >> 11) * NH + (lcol >> 6)) * DK + (lcol & 63)) * SEQ + (row0 & 2047);
          *(int2*)(outvt + tidx) = pk.v;
        }
      } else if (atomf) {
        #pragma unroll
        for (int r = 0; r < 4; r++)
          atomicAdd(&atomf[(size_t)(row0 + r) * N + col], vals[r]);
      } else {
        #pragma unroll
        for (int r = 0; r < 4; r++) {
          const size_t idx = (size_t)(row0 + r) * N + col;
          if (outf) outf[idx] = vals[r];
          if (outb) outb[idx] = f2bf(vals[r]);
        }
      }
    }
  }
}

// ---------------- MFMA flash attention (v3: log2-domain softmax) --------------
// Block = 4 waves, 64 Q-rows of one (b,h). KV tiles of 64. Online softmax.
// QK^T computed as mfma(K,Q) so each lane owns ONE q-column (q = wv*16+l15) with
// kv in the register dim: row max/sum are lane-local + 2 shfl_xor, m/l/alpha
// scalars. Scores kept in log2 domain (0.125*log2e folded into the score FMA)
// so P/alpha are single native v_exp_f32 (2^x) each. P packed via cvt_pk bf16.
// LDS tiles are [64][64] shorts with XOR swizzle col^=(row&7)<<3 (16B granules).
// K/V staged via global_load_lds with PRE-SWIZZLED global source (m173 pattern).
// Og may alias Qg (Q frags register-resident before any write).
#define AQT 64
#define AKT 64
__global__ __launch_bounds__(256) void attn_mfma(
    const unsigned short* __restrict__ Qg,   // [B*S][D_MODEL] bf16
    const unsigned short* __restrict__ Kg,   // [B*S][D_MODEL] bf16
    const unsigned short* __restrict__ Vt,   // [(b*NH+h)*DK + d][SEQ] bf16 (transposed)
    const int* __restrict__ mask,            // [B*S]
    unsigned short* __restrict__ Og)
{
  __shared__ __attribute__((aligned(16))) short Ks[AKT * 64];
  __shared__ __attribute__((aligned(16))) short Vs[DK * 64];
  __shared__ __attribute__((aligned(16))) short Ps[AQT * 64];
  __shared__ __attribute__((aligned(16))) float maddf[AKT];

  const int bid = blockIdx.x;
  const int nqt = SEQ / AQT;          // 32
  const int b  = bid / (NH * nqt);
  const int h  = (bid / nqt) % NH;
  const int q0 = (bid % nqt) * AQT;
  const int t  = threadIdx.x;
  const int wv = t >> 6, lane = t & 63;
  const int quad = lane >> 4, l15 = lane & 15;
  const int sw = (l15 & 7) << 3;      // shared XOR swizzle for all row&7==l15&7 reads
  const float SCL = 0.125f * 1.44269504f;   // score scale in log2 domain

  bf16x8 qf0, qf1;
  {
    const unsigned short* qrow = Qg + (size_t)(b * SEQ + q0 + wv * 16 + l15) * D_MODEL + h * DK;
    qf0 = *(const bf16x8*)(qrow + quad * 8);
    qf1 = *(const bf16x8*)(qrow + 32 + quad * 8);
  }
  f32x4 oacc[4] = {};
  float m_run = -1e30f, l_run = 0.0f;

  const unsigned short* Kbase = Kg + (size_t)(b * SEQ) * D_MODEL + h * DK;
  const unsigned short* Vbase = Vt + ((size_t)(b * NH + h) * DK) * SEQ;

  for (int kt = 0; kt < SEQ; kt += AKT) {
    // stage K,V tiles: 512 x 16B segments each; LDS linear, global col pre-swizzled
    #pragma unroll
    for (int it = 0; it < 2; it++) {
      int s = it * 256 + t;
      int row = s >> 3;
      int scol = ((s & 7) * 8) ^ ((row & 7) << 3);
      gl_lds16(Kbase + (size_t)(kt + row) * D_MODEL + scol, &Ks[s * 8]);
      gl_lds16(Vbase + (size_t)row * SEQ + kt + scol, &Vs[s * 8]);
    }
    if (t < AKT) maddf[t] = mask[b * SEQ + kt + t] ? 0.0f : -1.0e9f;
    __syncthreads();

    // swapped QK^T: out[m=kv=ct*16+quad*4+r][n=q=l15]; scores in log2 domain
    f32x4 sc[4];
    #pragma unroll
    for (int ct = 0; ct < 4; ct++) {
      const int krow = ct * 16 + l15;
      bf16x8 kb0 = *(const bf16x8*)&Ks[krow * 64 + ((quad * 8) ^ sw)];
      bf16x8 kb1 = *(const bf16x8*)&Ks[krow * 64 + ((32 + quad * 8) ^ sw)];
      f32x4 a = {};
      a = __builtin_amdgcn_mfma_f32_16x16x32_bf16(kb0, qf0, a, 0, 0, 0);
      a = __builtin_amdgcn_mfma_f32_16x16x32_bf16(kb1, qf1, a, 0, 0, 0);
      f32x4 md = *(const f32x4*)&maddf[ct * 16 + quad * 4];
      #pragma unroll
      for (int r = 0; r < 4; r++) a[r] = a[r] * SCL + md[r];
      sc[ct] = a;
    }

    // lane-local row max over 16 kv values, then combine the 4 quads
    float tmax = sc[0][0];
    #pragma unroll
    for (int ct = 0; ct < 4; ct++)
      #pragma unroll
      for (int r = 0; r < 4; r++) tmax = fmaxf(tmax, sc[ct][r]);
    tmax = fmaxf(tmax, __shfl_xor(tmax, 16));
    tmax = fmaxf(tmax, __shfl_xor(tmax, 32));

    // defer-max (T13): only rescale when max grew by > 8 nats (11.54 in log2)
    if (!__all(tmax - m_run <= 11.5415603f)) {
      float mn = fmaxf(m_run, tmax);
      float alpha = fexp2(m_run - mn);
      m_run = mn;
      l_run *= alpha;
      float a4[4];
      #pragma unroll
      for (int r = 0; r < 4; r++) a4[r] = __shfl(alpha, quad * 4 + r);
      #pragma unroll
      for (int dt = 0; dt < 4; dt++)
        #pragma unroll
        for (int r = 0; r < 4; r++) oacc[dt][r] *= a4[r];
    }

    // P = 2^(S - m); packed bf16 store: 4x ds_write_b64 (P[q][kv] layout, swizzled)
    const int prow = wv * 16 + l15;
    float rs = 0.0f;
    #pragma unroll
    for (int ct = 0; ct < 4; ct++) {
      float p0 = fexp2(sc[ct][0] - m_run);
      float p1 = fexp2(sc[ct][1] - m_run);
      float p2 = fexp2(sc[ct][2] - m_run);
      float p3 = fexp2(sc[ct][3] - m_run);
      rs += (p0 + p1) + (p2 + p3);
      unsigned int lo, hi;
      asm("v_cvt_pk_bf16_f32 %0, %1, %2" : "=v"(lo) : "v"(p0), "v"(p1));
      asm("v_cvt_pk_bf16_f32 %0, %1, %2" : "=v"(hi) : "v"(p2), "v"(p3));
      int2 pv; pv.x = (int)lo; pv.y = (int)hi;
      *(int2*)&Ps[prow * 64 + ((ct * 16 + quad * 4) ^ sw)] = pv;
    }
    rs += __shfl_xor(rs, 16);
    rs += __shfl_xor(rs, 32);
    l_run += rs;

    // PV: A = P[q][kv 8-contig] (own wave's rows), B = V[kv][d] from Vs[d][kv]
    bf16x8 pf0 = *(const bf16x8*)&Ps[prow * 64 + ((quad * 8) ^ sw)];
    bf16x8 pf1 = *(const bf16x8*)&Ps[prow * 64 + ((32 + quad * 8) ^ sw)];
    #pragma unroll
    for (int dt = 0; dt < 4; dt++) {
      const int vrow = dt * 16 + l15;
      bf16x8 vb0 = *(const bf16x8*)&Vs[vrow * 64 + ((quad * 8) ^ sw)];
      bf16x8 vb1 = *(const bf16x8*)&Vs[vrow * 64 + ((32 + quad * 8) ^ sw)];
      oacc[dt] = __builtin_amdgcn_mfma_f32_16x16x32_bf16(pf0, vb0, oacc[dt], 0, 0, 0);
      oacc[dt] = __builtin_amdgcn_mfma_f32_16x16x32_bf16(pf1, vb1, oacc[dt], 0, 0, 0);
    }
    __syncthreads();
  }

  // transport 1/l from lane-layout (q=l15) to C-layout (q=quad*4+r)
  float li = 1.0f / l_run;
  float linv4[4];
  #pragma unroll
  for (int r = 0; r < 4; r++) linv4[r] = __shfl(li, quad * 4 + r);
  #pragma unroll
  for (int dt = 0; dt < 4; dt++)
    #pragma unroll
    for (int r = 0; r < 4; r++)
      Og[(size_t)(b * SEQ + q0 + wv * 16 + quad * 4 + r) * D_MODEL + h * DK + dt * 16 + l15] =
        f2bf(oacc[dt][r] * linv4[r]);
}

// ---------------- launch ----------------
// fp32 I/O. All GEMMs bf16 with just-in-time weight conversion. NO ws_size gate.
// ws high-water 48MB:
//   phase A: q [0,16)  k [16,32)  vt [32,48)
//   phase B (after attn): ao=q, wo16 -> [16,18) (k dead)
//   phase C (after o-proj): w1 -> [0,8), w2 -> [8,16) (ao dead); ln2 -> [32,48)
//            hff chunk -> [16,32)
// d_out as scratch: ln1b [0,16MB), wqkv16 [16,22MB); o-proj overwrites all with x1 fp32.
extern "C" void kernel_launch(void* const* d_in, const int* in_sizes, int n_in,
                              void* d_out, int out_size, void* d_ws, size_t ws_size,
                              hipStream_t stream)
{
  (void)in_sizes; (void)n_in; (void)out_size; (void)ws_size;
  const float* x   = (const float*)d_in[0];
  const int*   msk = (const int*)d_in[1];
  const float* w_q = (const float*)d_in[2];
  const float* w_k = (const float*)d_in[3];
  const float* w_v = (const float*)d_in[4];
  const float* w_o = (const float*)d_in[5];
  const float* w1  = (const float*)d_in[6];
  const float* b1  = (const float*)d_in[7];
  const float* w2  = (const float*)d_in[8];
  const float* b2  = (const float*)d_in[9];
  const float* g1  = (const float*)d_in[10];
  const float* be1 = (const float*)d_in[11];
  const float* g2  = (const float*)d_in[12];
  const float* be2 = (const float*)d_in[13];
  float* outf = (float*)d_out;

  char* ws = (char*)d_ws;
  const size_t MB = 1024 * 1024;
  unsigned short* q_b  = (unsigned short*)(ws + 0);        // 16MB -> ao
  unsigned short* k_b  = (unsigned short*)(ws + 16 * MB);  // 16MB -> wo16 -> hff chunk
  unsigned short* vt_b = (unsigned short*)(ws + 32 * MB);  // 16MB -> ln2b
  unsigned short* wo16 = (unsigned short*)(ws + 16 * MB);  // 2MB (k dead after attn)
  unsigned short* w116 = (unsigned short*)(ws + 0);        // 8MB (ao dead after o-proj)
  unsigned short* w216 = (unsigned short*)(ws + 8 * MB);   // 8MB
  unsigned short* ln2b = vt_b;                             // 16MB (vt dead after attn)
  unsigned short* hffc = k_b;                              // 16MB chunk

  unsigned short* ln1b   = (unsigned short*)d_out;                  // [0,16MB) of d_out
  unsigned short* wqkv16 = (unsigned short*)d_out + 8 * 1024 * 1024;// [16,22MB) of d_out

  dim3 blk(256);
  const int nw = D_MODEL * D_MODEL;  // 1M elems
  const int nf = DFF * D_MODEL;      // 4M elems

  // phase A: weights q|k|v -> fused bf16 [3072,1024] in d_out scratch; LN1
  cvt_f2b<<<nw / 1024, blk, 0, stream>>>(w_q, wqkv16, nw);
  cvt_f2b<<<nw / 1024, blk, 0, stream>>>(w_k, wqkv16 + nw, nw);
  cvt_f2b<<<nw / 1024, blk, 0, stream>>>(w_v, wqkv16 + 2 * nw, nw);
  ln_kernel<<<NROWS, blk, 0, stream>>>(x, g1, be1, ln1b);

  // fused QKV: [8192,1024] x [3072,1024]^T -> q, k, vt
  dim3 gqkv(3 * D_MODEL / 128, NROWS / 128);  // (24, 64) = 1536 blocks
  gemm_bt<<<gqkv, blk, 0, stream>>>(ln1b, wqkv16, D_MODEL, 3 * D_MODEL, D_MODEL, D_MODEL,
                                    nullptr, 0, nullptr, nullptr, nullptr, nullptr,
                                    q_b, k_b, vt_b);

  // attention (output in-place over q)
  attn_mfma<<<BATCH * NH * (SEQ / AQT), blk, 0, stream>>>(q_b, k_b, vt_b, msk, q_b);

  // phase B: wo -> dead k region; o-proj + residual(x) -> x1 = d_out (fp32)
  cvt_f2b<<<nw / 1024, blk, 0, stream>>>(w_o, wo16, nw);
  dim3 gN1024(D_MODEL / 128, NROWS / 128);  // (8, 64)
  gemm_bt<<<gN1024, blk, 0, stream>>>(q_b, wo16, D_MODEL, D_MODEL, D_MODEL, D_MODEL,
                                      nullptr, 0, x, nullptr, outf, nullptr,
                                      nullptr, nullptr, nullptr);

  // phase C: w1/w2 -> dead ao region; LN2 -> dead vt region; chunked FFN
  cvt_f2b<<<nf / 1024, blk, 0, stream>>>(w1, w116, nf);
  cvt_f2b<<<nf / 1024, blk, 0, stream>>>(w2, w216, nf);
  ln_kernel<<<NROWS, blk, 0, stream>>>(outf, g2, be2, ln2b);
  for (int c = 0; c < NCHUNK; c++) {
    const size_t ro = (size_t)c * CHUNK;
    dim3 g1c(DFF / 128,     CHUNK / 128);      // (32, 16) = 512 blocks
    dim3 g2c(D_MODEL / 128, CHUNK / 128, 4);   // (8, 16, 4) = 512 blocks, split-K
    gemm_bt<<<g1c, blk, 0, stream>>>(ln2b + ro * D_MODEL, w116, D_MODEL, DFF,
                                     D_MODEL, D_MODEL, b1, 1,
                                     nullptr, hffc, nullptr, nullptr,
                                     nullptr, nullptr, nullptr);
    // FFN2 split-K=4 (K=1024 each): outf already holds x1 (residual) in place;
    // partials accumulate via device-scope fp32 atomics, bias from split 0.
    gemm_bt<<<g2c, blk, 0, stream>>>(hffc, w216, DFF / 4, D_MODEL, DFF, DFF, b2, 0,
                                     nullptr, nullptr, nullptr, outf + ro * D_MODEL,
                                     nullptr, nullptr, nullptr);
  }
}

// Round 4
// 727.176 us; speedup vs baseline: 1.4753x; 1.0647x over previous
//
#include <hip/hip_runtime.h>

#define D_MODEL 1024
#define NH 16
#define DK 64
#define DFF 4096
#define SEQ 2048
#define BATCH 4
#define NROWS (BATCH*SEQ)   // 8192
#define CHUNK 2048          // FFN row-chunk (16MB bf16 hidden fits dead k region)
#define NCHUNK (NROWS/CHUNK)

typedef short bf16x8 __attribute__((ext_vector_type(8)));
typedef float f32x4 __attribute__((ext_vector_type(4)));

__device__ __forceinline__ float bf2f(unsigned short u){
  union { float f; unsigned int i; } x; x.i = ((unsigned int)u) << 16; return x.f;
}
__device__ __forceinline__ unsigned short f2bf(float f){
  union { float f; unsigned int i; } x; x.f = f;
  unsigned int r = x.i + 0x7fffu + ((x.i >> 16) & 1u);
  return (unsigned short)(r >> 16);
}
__device__ __forceinline__ float fexp2(float x){
#if __has_builtin(__builtin_amdgcn_exp2f)
  return __builtin_amdgcn_exp2f(x);
#else
  return __exp2f(x);
#endif
}

// async global->LDS, 16B per lane (m97 pattern; LDS dest = wave base + lane*16)
__device__ __forceinline__ void gl_lds16(const void* g, void* l) {
  __builtin_amdgcn_global_load_lds((const __attribute__((address_space(1))) void*)g,
                                   (__attribute__((address_space(3))) void*)l, 16, 0, 0);
}

// ---------------- fp32 -> bf16 bulk convert (weights) ----------------
__global__ __launch_bounds__(256) void cvt_f2b(const float* __restrict__ in,
                                               unsigned short* __restrict__ out, int n)
{
  int i = (blockIdx.x * 256 + threadIdx.x) * 4;
  if (i < n) {
    float4 f = *(const float4*)(in + i);
    union { int2 v; unsigned short u[4]; } o;
    o.u[0] = f2bf(f.x); o.u[1] = f2bf(f.y); o.u[2] = f2bf(f.z); o.u[3] = f2bf(f.w);
    *(int2*)(out + i) = o.v;
  }
}

// ---------------- LayerNorm: fp32 in -> bf16 out, one block per row of 1024 ----
// torch variant: unbiased std (ddof=1), eps added to std (not var)
__global__ __launch_bounds__(256) void ln_kernel(const float* __restrict__ in,
    const float* __restrict__ gam, const float* __restrict__ bet,
    unsigned short* __restrict__ out)
{
  const int row = blockIdx.x, t = threadIdx.x;
  const int base = t * 4;
  float4 raw = *(const float4*)(in + (size_t)row * D_MODEL + base);
  float v[4] = { raw.x, raw.y, raw.z, raw.w };
  float s  = v[0] + v[1] + v[2] + v[3];
  float s2 = v[0]*v[0] + v[1]*v[1] + v[2]*v[2] + v[3]*v[3];
  #pragma unroll
  for (int off = 32; off > 0; off >>= 1) {
    s  += __shfl_down(s,  off);
    s2 += __shfl_down(s2, off);
  }
  __shared__ float red[10];
  const int wid = t >> 6, lane = t & 63;
  if (lane == 0) { red[wid] = s; red[4 + wid] = s2; }
  __syncthreads();
  if (t == 0) {
    float ts  = red[0] + red[1] + red[2] + red[3];
    float ts2 = red[4] + red[5] + red[6] + red[7];
    float mean = ts * (1.0f / D_MODEL);
    float var  = (ts2 - (float)D_MODEL * mean * mean) * (1.0f / (D_MODEL - 1));
    var = fmaxf(var, 0.0f);
    red[8] = mean;
    red[9] = 1.0f / (sqrtf(var) + 1e-6f);
  }
  __syncthreads();
  const float mean = red[8], inv = red[9];
  float4 g4 = *(const float4*)(gam + base);
  float4 b4 = *(const float4*)(bet + base);
  union { int2 v; unsigned short u[4]; } o;
  o.u[0] = f2bf(g4.x * (v[0] - mean) * inv + b4.x);
  o.u[1] = f2bf(g4.y * (v[1] - mean) * inv + b4.y);
  o.u[2] = f2bf(g4.z * (v[2] - mean) * inv + b4.z);
  o.u[3] = f2bf(g4.w * (v[3] - mean) * inv + b4.w);
  *(int2*)(out + (size_t)row * D_MODEL + base) = o.v;
}

// ---------------- GEMM: C[m,n] = sum_k A[m,k] * Bw[n,k]  (+ epilogue) ----------
// All-bf16 operands; 2-phase pipeline: prefetch K-step t+1 via global_load_lds
// into the ALTERNATE static LDS buffer BEFORE computing step t (T3-minimum).
// Static buffer identity (2x-unrolled loop) so alias analysis keeps the
// prefetch un-serialized; the only vmcnt(0) drain is the one __syncthreads()
// emits AFTER compute. One barrier per K-step.
// 128x128 tile, BK=32, 4 waves (2x2), each wave 64x64 via 4x4 mfma_16x16x32_bf16.
// QKV mode (outq!=null): N=3072 fused; col block 0->q, 1->k, 2->vt (transposed).
// Split-K mode (atomf!=null): grid.z = #splits, each handles K cols
//   [z*K, (z+1)*K); epilogue atomicAdd fp32 (bias by z==0 only).
//   Target must be pre-initialized (residual).
__global__ __launch_bounds__(256) void gemm_bt(
    const unsigned short* __restrict__ A,   // [M,*] bf16, row stride sA
    const unsigned short* __restrict__ Bw,  // [N,*] bf16, row stride sB
    int K, int N, int sA, int sB,
    const float* __restrict__ bias,    // [N] fp32 or null
    int relu,
    const float* __restrict__ residf,  // [M,N] fp32 or null
    unsigned short* __restrict__ outb, // [M,N] bf16 or null
    float* __restrict__ outf,          // [M,N] fp32 or null
    float* __restrict__ atomf,         // [M,N] fp32 atomic-accum or null
    unsigned short* __restrict__ outq, // fused-QKV q  [M,1024] or null
    unsigned short* __restrict__ outk, //           k  [M,1024]
    unsigned short* __restrict__ outvt)//           v^T [(b,h),d,s]
{
  __shared__ __attribute__((aligned(16))) short sA0[128 * 32];
  __shared__ __attribute__((aligned(16))) short sA1[128 * 32];
  __shared__ __attribute__((aligned(16))) short sB0[128 * 32];
  __shared__ __attribute__((aligned(16))) short sB1[128 * 32];
  const int t = threadIdx.x;
  const int tileN = blockIdx.x * 128;
  const int tileM = blockIdx.y * 128;
  const int kz = blockIdx.z;
  const size_t koff = (size_t)kz * K;
  const int wid = t >> 6, lane = t & 63;
  const int wM = (wid >> 1) * 64, wN = (wid & 1) * 64;
  const int quad = lane >> 4, lrow = lane & 15;

  f32x4 acc[4][4] = {};

  auto stage = [&](short* dA, short* dB, int k0) {
    #pragma unroll
    for (int it2 = 0; it2 < 2; it2++) {
      int seg = it2 * 256 + t;            // 512 x 16B segments per 8KB tile
      int row = seg >> 2, c8 = (seg & 3) * 8;
      gl_lds16(A  + (size_t)(tileM + row) * sA + koff + k0 + c8, dA + seg * 8);
      gl_lds16(Bw + (size_t)(tileN + row) * sB + koff + k0 + c8, dB + seg * 8);
    }
  };
  auto compute = [&](const short* cA, const short* cB) {
    bf16x8 af[4], bfr[4];
    #pragma unroll
    for (int i = 0; i < 4; i++) {
      af[i]  = *(const bf16x8*)&cA[(wM + i * 16 + lrow) * 32 + quad * 8];
      bfr[i] = *(const bf16x8*)&cB[(wN + i * 16 + lrow) * 32 + quad * 8];
    }
    #pragma unroll
    for (int i = 0; i < 4; i++)
      #pragma unroll
      for (int j = 0; j < 4; j++)
        acc[i][j] = __builtin_amdgcn_mfma_f32_16x16x32_bf16(af[i], bfr[j], acc[i][j], 0, 0, 0);
  };

  const int nk = K >> 5;                 // always even for our shapes (K=1024)
  stage(sA0, sB0, 0);
  __syncthreads();
  for (int ik = 0; ik < nk; ik += 2) {
    if (ik + 1 < nk) stage(sA1, sB1, (ik + 1) << 5);
    compute(sA0, sB0);
    __syncthreads();
    if (ik + 2 < nk) stage(sA0, sB0, (ik + 2) << 5);
    compute(sA1, sB1);
    __syncthreads();
  }

  // fused-QKV epilogue target for this block (tileN is 128-aligned; one cat/block)
  unsigned short* qk_out = nullptr;
  int qkv_cat = 0;
  if (outq) {
    qkv_cat = tileN >> 10;                 // 0=q 1=k 2=v
    qk_out = (qkv_cat == 0) ? outq : outk;
  }

  #pragma unroll
  for (int i = 0; i < 4; i++) {
    #pragma unroll
    for (int j = 0; j < 4; j++) {
      const int col  = tileN + wN + j * 16 + lrow;
      const int row0 = tileM + wM + i * 16 + quad * 4;
      const float bv = (bias && kz == 0) ? bias[col] : 0.0f;
      float vals[4];
      #pragma unroll
      for (int r = 0; r < 4; r++) {
        float val = acc[i][j][r] + bv;
        if (relu) val = fmaxf(val, 0.0f);
        if (residf) val += residf[(size_t)(row0 + r) * N + col];
        vals[r] = val;
      }
      if (outq) {
        const int lcol = col & 1023;
        if (qkv_cat < 2) {
          #pragma unroll
          for (int r = 0; r < 4; r++)
            qk_out[(size_t)(row0 + r) * D_MODEL + lcol] = f2bf(vals[r]);
        } else {
          // vt[((b*NH+h)*DK+d)*SEQ + s]: b=row>>11, s=row&2047, h=lcol>>6, d=lcol&63
          union { int2 v; unsigned short u[4]; } pk;
          #pragma unroll
          for (int r = 0; r < 4; r++) pk.u[r] = f2bf(vals[r]);
          size_t tidx = (((size_t)(row0 >> 11) * NH + (lcol >> 6)) * DK + (lcol & 63)) * SEQ + (row0 & 2047);
          *(int2*)(outvt + tidx) = pk.v;
        }
      } else if (atomf) {
        #pragma unroll
        for (int r = 0; r < 4; r++)
          atomicAdd(&atomf[(size_t)(row0 + r) * N + col], vals[r]);
      } else {
        #pragma unroll
        for (int r = 0; r < 4; r++) {
          const size_t idx = (size_t)(row0 + r) * N + col;
          if (outf) outf[idx] = vals[r];
          if (outb) outb[idx] = f2bf(vals[r]);
        }
      }
    }
  }
}

// ---------------- MFMA flash attention (v4: 2-phase KV prefetch) --------------
// Block = 4 waves, 64 Q-rows of one (b,h). KV tiles of 64. Online softmax.
// Swapped QK^T (mfma(K,Q)): lane owns one q-column, kv in register dim ->
// lane-local max/sum + 2 shfl_xor, scalar m/l/alpha, log2-domain exp.
// 2-phase: prefetch KV tile t+1 (global_load_lds, static alternate buffers)
// BEFORE computing tile t; ONE barrier per tile. Static buffer identity via
// 2x-unrolled tile loop keeps the prefetch un-serialized by alias analysis.
// LDS tiles [64][64] shorts, XOR swizzle col^=(row&7)<<3 (16B granules);
// K/V staged with PRE-SWIZZLED global source (m173 pattern).
// Og may alias Qg (Q frags register-resident before any write).
#define AQT 64
#define AKT 64
__global__ __launch_bounds__(256) void attn_mfma(
    const unsigned short* __restrict__ Qg,   // [B*S][D_MODEL] bf16
    const unsigned short* __restrict__ Kg,   // [B*S][D_MODEL] bf16
    const unsigned short* __restrict__ Vt,   // [(b*NH+h)*DK + d][SEQ] bf16 (transposed)
    const int* __restrict__ mask,            // [B*S]
    unsigned short* __restrict__ Og)
{
  __shared__ __attribute__((aligned(16))) short Ks0[AKT * 64];
  __shared__ __attribute__((aligned(16))) short Ks1[AKT * 64];
  __shared__ __attribute__((aligned(16))) short Vs0[DK * 64];
  __shared__ __attribute__((aligned(16))) short Vs1[DK * 64];
  __shared__ __attribute__((aligned(16))) short Psm[AQT * 64];
  __shared__ __attribute__((aligned(16))) float mf0[AKT];
  __shared__ __attribute__((aligned(16))) float mf1[AKT];

  const int bid = blockIdx.x;
  const int nqt = SEQ / AQT;          // 32
  const int b  = bid / (NH * nqt);
  const int h  = (bid / nqt) % NH;
  const int q0 = (bid % nqt) * AQT;
  const int t  = threadIdx.x;
  const int wv = t >> 6, lane = t & 63;
  const int quad = lane >> 4, l15 = lane & 15;
  const int sw = (l15 & 7) << 3;      // shared XOR swizzle for all row&7==l15&7 reads
  const float SCL = 0.125f * 1.44269504f;   // score scale in log2 domain

  bf16x8 qf0, qf1;
  {
    const unsigned short* qrow = Qg + (size_t)(b * SEQ + q0 + wv * 16 + l15) * D_MODEL + h * DK;
    qf0 = *(const bf16x8*)(qrow + quad * 8);
    qf1 = *(const bf16x8*)(qrow + 32 + quad * 8);
  }
  f32x4 oacc[4] = {};
  float m_run = -1e30f, l_run = 0.0f;

  const unsigned short* Kbase = Kg + (size_t)(b * SEQ) * D_MODEL + h * DK;
  const unsigned short* Vbase = Vt + ((size_t)(b * NH + h) * DK) * SEQ;

  auto stageKV = [&](short* kd, short* vd, float* mf, int kt) {
    #pragma unroll
    for (int it2 = 0; it2 < 2; it2++) {
      int s = it2 * 256 + t;
      int row = s >> 3;
      int scol = ((s & 7) * 8) ^ ((row & 7) << 3);
      gl_lds16(Kbase + (size_t)(kt + row) * D_MODEL + scol, kd + s * 8);
      gl_lds16(Vbase + (size_t)row * SEQ + kt + scol, vd + s * 8);
    }
    if (t < AKT) mf[t] = mask[b * SEQ + kt + t] ? 0.0f : -1.0e9f;
  };

  auto tilecomp = [&](const short* Ksc, const short* Vsc, const float* mfc) {
    // swapped QK^T: out[m=kv=ct*16+quad*4+r][n=q=l15]; scores in log2 domain
    f32x4 sc[4];
    #pragma unroll
    for (int ct = 0; ct < 4; ct++) {
      const int krow = ct * 16 + l15;
      bf16x8 kb0 = *(const bf16x8*)&Ksc[krow * 64 + ((quad * 8) ^ sw)];
      bf16x8 kb1 = *(const bf16x8*)&Ksc[krow * 64 + ((32 + quad * 8) ^ sw)];
      f32x4 a = {};
      a = __builtin_amdgcn_mfma_f32_16x16x32_bf16(kb0, qf0, a, 0, 0, 0);
      a = __builtin_amdgcn_mfma_f32_16x16x32_bf16(kb1, qf1, a, 0, 0, 0);
      f32x4 md = *(const f32x4*)&mfc[ct * 16 + quad * 4];
      #pragma unroll
      for (int r = 0; r < 4; r++) a[r] = a[r] * SCL + md[r];
      sc[ct] = a;
    }

    // lane-local row max over 16 kv values, then combine the 4 quads
    float tmax = sc[0][0];
    #pragma unroll
    for (int ct = 0; ct < 4; ct++)
      #pragma unroll
      for (int r = 0; r < 4; r++) tmax = fmaxf(tmax, sc[ct][r]);
    tmax = fmaxf(tmax, __shfl_xor(tmax, 16));
    tmax = fmaxf(tmax, __shfl_xor(tmax, 32));

    // defer-max (T13): only rescale when max grew by > 8 nats (11.54 in log2)
    if (!__all(tmax - m_run <= 11.5415603f)) {
      float mn = fmaxf(m_run, tmax);
      float alpha = fexp2(m_run - mn);
      m_run = mn;
      l_run *= alpha;
      float a4[4];
      #pragma unroll
      for (int r = 0; r < 4; r++) a4[r] = __shfl(alpha, quad * 4 + r);
      #pragma unroll
      for (int dt = 0; dt < 4; dt++)
        #pragma unroll
        for (int r = 0; r < 4; r++) oacc[dt][r] *= a4[r];
    }

    // P = 2^(S - m); packed bf16 store: 4x ds_write_b64 (P[q][kv] layout, swizzled)
    const int prow = wv * 16 + l15;
    float rs = 0.0f;
    #pragma unroll
    for (int ct = 0; ct < 4; ct++) {
      float p0 = fexp2(sc[ct][0] - m_run);
      float p1 = fexp2(sc[ct][1] - m_run);
      float p2 = fexp2(sc[ct][2] - m_run);
      float p3 = fexp2(sc[ct][3] - m_run);
      rs += (p0 + p1) + (p2 + p3);
      unsigned int lo, hi;
      asm("v_cvt_pk_bf16_f32 %0, %1, %2" : "=v"(lo) : "v"(p0), "v"(p1));
      asm("v_cvt_pk_bf16_f32 %0, %1, %2" : "=v"(hi) : "v"(p2), "v"(p3));
      int2 pv; pv.x = (int)lo; pv.y = (int)hi;
      *(int2*)&Psm[prow * 64 + ((ct * 16 + quad * 4) ^ sw)] = pv;
    }
    rs += __shfl_xor(rs, 16);
    rs += __shfl_xor(rs, 32);
    l_run += rs;

    // PV: A = P[q][kv 8-contig] (own wave's rows), B = V[kv][d] from Vs[d][kv]
    bf16x8 pf0 = *(const bf16x8*)&Psm[prow * 64 + ((quad * 8) ^ sw)];
    bf16x8 pf1 = *(const bf16x8*)&Psm[prow * 64 + ((32 + quad * 8) ^ sw)];
    #pragma unroll
    for (int dt = 0; dt < 4; dt++) {
      const int vrow = dt * 16 + l15;
      bf16x8 vb0 = *(const bf16x8*)&Vsc[vrow * 64 + ((quad * 8) ^ sw)];
      bf16x8 vb1 = *(const bf16x8*)&Vsc[vrow * 64 + ((32 + quad * 8) ^ sw)];
      oacc[dt] = __builtin_amdgcn_mfma_f32_16x16x32_bf16(pf0, vb0, oacc[dt], 0, 0, 0);
      oacc[dt] = __builtin_amdgcn_mfma_f32_16x16x32_bf16(pf1, vb1, oacc[dt], 0, 0, 0);
    }
  };

  stageKV(Ks0, Vs0, mf0, 0);
  __syncthreads();
  for (int it = 0; it < SEQ / AKT; it += 2) {
    const int kt = it * AKT;
    if (it + 1 < SEQ / AKT) stageKV(Ks1, Vs1, mf1, kt + AKT);
    tilecomp(Ks0, Vs0, mf0);
    __syncthreads();
    if (it + 2 < SEQ / AKT) stageKV(Ks0, Vs0, mf0, kt + 2 * AKT);
    tilecomp(Ks1, Vs1, mf1);
    __syncthreads();
  }

  // transport 1/l from lane-layout (q=l15) to C-layout (q=quad*4+r)
  float li = 1.0f / l_run;
  float linv4[4];
  #pragma unroll
  for (int r = 0; r < 4; r++) linv4[r] = __shfl(li, quad * 4 + r);
  #pragma unroll
  for (int dt = 0; dt < 4; dt++)
    #pragma unroll
    for (int r = 0; r < 4; r++)
      Og[(size_t)(b * SEQ + q0 + wv * 16 + quad * 4 + r) * D_MODEL + h * DK + dt * 16 + l15] =
        f2bf(oacc[dt][r] * linv4[r]);
}

// ---------------- launch ----------------
// fp32 I/O. All GEMMs bf16 with just-in-time weight conversion. NO ws_size gate.
// ws high-water 48MB:
//   phase A: q [0,16)  k [16,32)  vt [32,48)
//   phase B (after attn): ao=q, wo16 -> [16,18) (k dead)
//   phase C (after o-proj): w1 -> [0,8), w2 -> [8,16) (ao dead); ln2 -> [32,48)
//            hff chunk -> [16,32)
// d_out as scratch: ln1b [0,16MB), wqkv16 [16,22MB); o-proj overwrites all with x1 fp32.
extern "C" void kernel_launch(void* const* d_in, const int* in_sizes, int n_in,
                              void* d_out, int out_size, void* d_ws, size_t ws_size,
                              hipStream_t stream)
{
  (void)in_sizes; (void)n_in; (void)out_size; (void)ws_size;
  const float* x   = (const float*)d_in[0];
  const int*   msk = (const int*)d_in[1];
  const float* w_q = (const float*)d_in[2];
  const float* w_k = (const float*)d_in[3];
  const float* w_v = (const float*)d_in[4];
  const float* w_o = (const float*)d_in[5];
  const float* w1  = (const float*)d_in[6];
  const float* b1  = (const float*)d_in[7];
  const float* w2  = (const float*)d_in[8];
  const float* b2  = (const float*)d_in[9];
  const float* g1  = (const float*)d_in[10];
  const float* be1 = (const float*)d_in[11];
  const float* g2  = (const float*)d_in[12];
  const float* be2 = (const float*)d_in[13];
  float* outf = (float*)d_out;

  char* ws = (char*)d_ws;
  const size_t MB = 1024 * 1024;
  unsigned short* q_b  = (unsigned short*)(ws + 0);        // 16MB -> ao
  unsigned short* k_b  = (unsigned short*)(ws + 16 * MB);  // 16MB -> wo16 -> hff chunk
  unsigned short* vt_b = (unsigned short*)(ws + 32 * MB);  // 16MB -> ln2b
  unsigned short* wo16 = (unsigned short*)(ws + 16 * MB);  // 2MB (k dead after attn)
  unsigned short* w116 = (unsigned short*)(ws + 0);        // 8MB (ao dead after o-proj)
  unsigned short* w216 = (unsigned short*)(ws + 8 * MB);   // 8MB
  unsigned short* ln2b = vt_b;                             // 16MB (vt dead after attn)
  unsigned short* hffc = k_b;                              // 16MB chunk

  unsigned short* ln1b   = (unsigned short*)d_out;                  // [0,16MB) of d_out
  unsigned short* wqkv16 = (unsigned short*)d_out + 8 * 1024 * 1024;// [16,22MB) of d_out

  dim3 blk(256);
  const int nw = D_MODEL * D_MODEL;  // 1M elems
  const int nf = DFF * D_MODEL;      // 4M elems

  // phase A: weights q|k|v -> fused bf16 [3072,1024] in d_out scratch; LN1
  cvt_f2b<<<nw / 1024, blk, 0, stream>>>(w_q, wqkv16, nw);
  cvt_f2b<<<nw / 1024, blk, 0, stream>>>(w_k, wqkv16 + nw, nw);
  cvt_f2b<<<nw / 1024, blk, 0, stream>>>(w_v, wqkv16 + 2 * nw, nw);
  ln_kernel<<<NROWS, blk, 0, stream>>>(x, g1, be1, ln1b);

  // fused QKV: [8192,1024] x [3072,1024]^T -> q, k, vt
  dim3 gqkv(3 * D_MODEL / 128, NROWS / 128);  // (24, 64) = 1536 blocks
  gemm_bt<<<gqkv, blk, 0, stream>>>(ln1b, wqkv16, D_MODEL, 3 * D_MODEL, D_MODEL, D_MODEL,
                                    nullptr, 0, nullptr, nullptr, nullptr, nullptr,
                                    q_b, k_b, vt_b);

  // attention (output in-place over q)
  attn_mfma<<<BATCH * NH * (SEQ / AQT), blk, 0, stream>>>(q_b, k_b, vt_b, msk, q_b);

  // phase B: wo -> dead k region; o-proj + residual(x) -> x1 = d_out (fp32)
  cvt_f2b<<<nw / 1024, blk, 0, stream>>>(w_o, wo16, nw);
  dim3 gN1024(D_MODEL / 128, NROWS / 128);  // (8, 64)
  gemm_bt<<<gN1024, blk, 0, stream>>>(q_b, wo16, D_MODEL, D_MODEL, D_MODEL, D_MODEL,
                                      nullptr, 0, x, nullptr, outf, nullptr,
                                      nullptr, nullptr, nullptr);

  // phase C: w1/w2 -> dead ao region; LN2 -> dead vt region; chunked FFN
  cvt_f2b<<<nf / 1024, blk, 0, stream>>>(w1, w116, nf);
  cvt_f2b<<<nf / 1024, blk, 0, stream>>>(w2, w216, nf);
  ln_kernel<<<NROWS, blk, 0, stream>>>(outf, g2, be2, ln2b);
  for (int c = 0; c < NCHUNK; c++) {
    const size_t ro = (size_t)c * CHUNK;
    dim3 g1c(DFF / 128,     CHUNK / 128);      // (32, 16) = 512 blocks
    dim3 g2c(D_MODEL / 128, CHUNK / 128, 4);   // (8, 16, 4) = 512 blocks, split-K
    gemm_bt<<<g1c, blk, 0, stream>>>(ln2b + ro * D_MODEL, w116, D_MODEL, DFF,
                                     D_MODEL, D_MODEL, b1, 1,
                                     nullptr, hffc, nullptr, nullptr,
                                     nullptr, nullptr, nullptr);
    // FFN2 split-K=4 (K=1024 each): outf already holds x1 (residual) in place;
    // partials accumulate via device-scope fp32 atomics, bias from split 0.
    gemm_bt<<<g2c, blk, 0, stream>>>(hffc, w216, DFF / 4, D_MODEL, DFF, DFF, b2, 0,
                                     nullptr, nullptr, nullptr, outf + ro * D_MODEL,
                                     nullptr, nullptr, nullptr);
  }
}

// Round 5
// 707.158 us; speedup vs baseline: 1.5171x; 1.0283x over previous
//
#include <hip/hip_runtime.h>

#define D_MODEL 1024
#define NH 16
#define DK 64
#define DFF 4096
#define SEQ 2048
#define BATCH 4
#define NROWS (BATCH*SEQ)   // 8192
#define CHUNK 2048          // FFN row-chunk (16MB bf16 hidden fits dead k region)
#define NCHUNK (NROWS/CHUNK)

typedef short bf16x8 __attribute__((ext_vector_type(8)));
typedef float f32x4 __attribute__((ext_vector_type(4)));

__device__ __forceinline__ float bf2f(unsigned short u){
  union { float f; unsigned int i; } x; x.i = ((unsigned int)u) << 16; return x.f;
}
__device__ __forceinline__ unsigned short f2bf(float f){
  union { float f; unsigned int i; } x; x.f = f;
  unsigned int r = x.i + 0x7fffu + ((x.i >> 16) & 1u);
  return (unsigned short)(r >> 16);
}
__device__ __forceinline__ float fexp2(float x){
#if __has_builtin(__builtin_amdgcn_exp2f)
  return __builtin_amdgcn_exp2f(x);
#else
  return __exp2f(x);
#endif
}

// async global->LDS, 16B per lane (m97 pattern; LDS dest = wave base + lane*16)
__device__ __forceinline__ void gl_lds16(const void* g, void* l) {
  __builtin_amdgcn_global_load_lds((const __attribute__((address_space(1))) void*)g,
                                   (__attribute__((address_space(3))) void*)l, 16, 0, 0);
}

// ---------------- fp32 -> bf16 bulk convert (weights) ----------------
__global__ __launch_bounds__(256) void cvt_f2b(const float* __restrict__ in,
                                               unsigned short* __restrict__ out, int n)
{
  int i = (blockIdx.x * 256 + threadIdx.x) * 4;
  if (i < n) {
    float4 f = *(const float4*)(in + i);
    union { int2 v; unsigned short u[4]; } o;
    o.u[0] = f2bf(f.x); o.u[1] = f2bf(f.y); o.u[2] = f2bf(f.z); o.u[3] = f2bf(f.w);
    *(int2*)(out + i) = o.v;
  }
}

// ---------------- LayerNorm: fp32 in -> bf16 out, one block per row of 1024 ----
// torch variant: unbiased std (ddof=1), eps added to std (not var)
__global__ __launch_bounds__(256) void ln_kernel(const float* __restrict__ in,
    const float* __restrict__ gam, const float* __restrict__ bet,
    unsigned short* __restrict__ out)
{
  const int row = blockIdx.x, t = threadIdx.x;
  const int base = t * 4;
  float4 raw = *(const float4*)(in + (size_t)row * D_MODEL + base);
  float v[4] = { raw.x, raw.y, raw.z, raw.w };
  float s  = v[0] + v[1] + v[2] + v[3];
  float s2 = v[0]*v[0] + v[1]*v[1] + v[2]*v[2] + v[3]*v[3];
  #pragma unroll
  for (int off = 32; off > 0; off >>= 1) {
    s  += __shfl_down(s,  off);
    s2 += __shfl_down(s2, off);
  }
  __shared__ float red[10];
  const int wid = t >> 6, lane = t & 63;
  if (lane == 0) { red[wid] = s; red[4 + wid] = s2; }
  __syncthreads();
  if (t == 0) {
    float ts  = red[0] + red[1] + red[2] + red[3];
    float ts2 = red[4] + red[5] + red[6] + red[7];
    float mean = ts * (1.0f / D_MODEL);
    float var  = (ts2 - (float)D_MODEL * mean * mean) * (1.0f / (D_MODEL - 1));
    var = fmaxf(var, 0.0f);
    red[8] = mean;
    red[9] = 1.0f / (sqrtf(var) + 1e-6f);
  }
  __syncthreads();
  const float mean = red[8], inv = red[9];
  float4 g4 = *(const float4*)(gam + base);
  float4 b4 = *(const float4*)(bet + base);
  union { int2 v; unsigned short u[4]; } o;
  o.u[0] = f2bf(g4.x * (v[0] - mean) * inv + b4.x);
  o.u[1] = f2bf(g4.y * (v[1] - mean) * inv + b4.y);
  o.u[2] = f2bf(g4.z * (v[2] - mean) * inv + b4.z);
  o.u[3] = f2bf(g4.w * (v[3] - mean) * inv + b4.w);
  *(int2*)(out + (size_t)row * D_MODEL + base) = o.v;
}

// ---------------- GEMM: C[m,n] = sum_k A[m,k] * Bw[n,k]  (+ epilogue) ----------
// All-bf16 operands; 2-phase pipeline: prefetch K-step t+1 via global_load_lds
// into the ALTERNATE static LDS buffer BEFORE computing step t (T3-minimum).
// Staging pointers hoisted: per-thread pa/pb advance by 32 elems per stage
// (no 64-bit addr recompute per step). One barrier per K-step.
// 128x128 tile, BK=32, 4 waves (2x2), each wave 64x64 via 4x4 mfma_16x16x32_bf16.
// QKV mode (outq!=null): N=3072 fused; col block 0->q, 1->k, 2->vt (transposed).
// Split-K mode (atomf!=null): grid.z = #splits, each handles K cols
//   [z*K, (z+1)*K); epilogue atomicAdd fp32 (bias by z==0 only).
//   Target must be pre-initialized (residual).
__global__ __launch_bounds__(256) void gemm_bt(
    const unsigned short* __restrict__ A,   // [M,*] bf16, row stride sA
    const unsigned short* __restrict__ Bw,  // [N,*] bf16, row stride sB
    int K, int N, int sA, int sB,
    const float* __restrict__ bias,    // [N] fp32 or null
    int relu,
    const float* __restrict__ residf,  // [M,N] fp32 or null
    unsigned short* __restrict__ outb, // [M,N] bf16 or null
    float* __restrict__ outf,          // [M,N] fp32 or null
    float* __restrict__ atomf,         // [M,N] fp32 atomic-accum or null
    unsigned short* __restrict__ outq, // fused-QKV q  [M,1024] or null
    unsigned short* __restrict__ outk, //           k  [M,1024]
    unsigned short* __restrict__ outvt)//           v^T [(b,h),d,s]
{
  __shared__ __attribute__((aligned(16))) short sA0[128 * 32];
  __shared__ __attribute__((aligned(16))) short sA1[128 * 32];
  __shared__ __attribute__((aligned(16))) short sB0[128 * 32];
  __shared__ __attribute__((aligned(16))) short sB1[128 * 32];
  const int t = threadIdx.x;
  const int tileN = blockIdx.x * 128;
  const int tileM = blockIdx.y * 128;
  const int kz = blockIdx.z;
  const size_t koff = (size_t)kz * K;
  const int wid = t >> 6, lane = t & 63;
  const int wM = (wid >> 1) * 64, wN = (wid & 1) * 64;
  const int quad = lane >> 4, lrow = lane & 15;

  f32x4 acc[4][4] = {};

  // hoisted staging pointers: thread t covers rows (t>>2) and (t>>2)+64, col (t&3)*8
  const unsigned short* pa = A  + (size_t)(tileM + (t >> 2)) * sA + koff + (t & 3) * 8;
  const unsigned short* pb = Bw + (size_t)(tileN + (t >> 2)) * sB + koff + (t & 3) * 8;
  const size_t a64 = (size_t)64 * sA, b64 = (size_t)64 * sB;

  auto stage = [&]() {
    gl_lds16(pa,       0 + t * 8 + (short*)nullptr); // placeholder avoided below
  };
  (void)stage;

  auto stageTo = [&](short* dA, short* dB) {
    gl_lds16(pa,       dA + t * 8);
    gl_lds16(pa + a64, dA + (256 + t) * 8);
    gl_lds16(pb,       dB + t * 8);
    gl_lds16(pb + b64, dB + (256 + t) * 8);
    pa += 32; pb += 32;
  };
  auto compute = [&](const short* cA, const short* cB) {
    bf16x8 af[4], bfr[4];
    #pragma unroll
    for (int i = 0; i < 4; i++) {
      af[i]  = *(const bf16x8*)&cA[(wM + i * 16 + lrow) * 32 + quad * 8];
      bfr[i] = *(const bf16x8*)&cB[(wN + i * 16 + lrow) * 32 + quad * 8];
    }
    #pragma unroll
    for (int i = 0; i < 4; i++)
      #pragma unroll
      for (int j = 0; j < 4; j++)
        acc[i][j] = __builtin_amdgcn_mfma_f32_16x16x32_bf16(af[i], bfr[j], acc[i][j], 0, 0, 0);
  };

  const int nk = K >> 5;                 // always even for our shapes
  stageTo(sA0, sB0);
  __syncthreads();
  for (int ik = 0; ik < nk; ik += 2) {
    if (ik + 1 < nk) stageTo(sA1, sB1);
    compute(sA0, sB0);
    __syncthreads();
    if (ik + 2 < nk) stageTo(sA0, sB0);
    compute(sA1, sB1);
    __syncthreads();
  }

  // fused-QKV epilogue target for this block (tileN is 128-aligned; one cat/block)
  unsigned short* qk_out = nullptr;
  int qkv_cat = 0;
  if (outq) {
    qkv_cat = tileN >> 10;                 // 0=q 1=k 2=v
    qk_out = (qkv_cat == 0) ? outq : outk;
  }

  #pragma unroll
  for (int i = 0; i < 4; i++) {
    #pragma unroll
    for (int j = 0; j < 4; j++) {
      const int col  = tileN + wN + j * 16 + lrow;
      const int row0 = tileM + wM + i * 16 + quad * 4;
      const float bv = (bias && kz == 0) ? bias[col] : 0.0f;
      float vals[4];
      #pragma unroll
      for (int r = 0; r < 4; r++) {
        float val = acc[i][j][r] + bv;
        if (relu) val = fmaxf(val, 0.0f);
        if (residf) val += residf[(size_t)(row0 + r) * N + col];
        vals[r] = val;
      }
      if (outq) {
        const int lcol = col & 1023;
        if (qkv_cat < 2) {
          #pragma unroll
          for (int r = 0; r < 4; r++)
            qk_out[(size_t)(row0 + r) * D_MODEL + lcol] = f2bf(vals[r]);
        } else {
          // vt[((b*NH+h)*DK+d)*SEQ + s]: b=row>>11, s=row&2047, h=lcol>>6, d=lcol&63
          union { int2 v; unsigned short u[4]; } pk;
          #pragma unroll
          for (int r = 0; r < 4; r++) pk.u[r] = f2bf(vals[r]);
          size_t tidx = (((size_t)(row0 >> 11) * NH + (lcol >> 6)) * DK + (lcol & 63)) * SEQ + (row0 & 2047);
          *(int2*)(outvt + tidx) = pk.v;
        }
      } else if (atomf) {
        #pragma unroll
        for (int r = 0; r < 4; r++)
          atomicAdd(&atomf[(size_t)(row0 + r) * N + col], vals[r]);
      } else {
        #pragma unroll
        for (int r = 0; r < 4; r++) {
          const size_t idx = (size_t)(row0 + r) * N + col;
          if (outf) outf[idx] = vals[r];
          if (outb) outb[idx] = f2bf(vals[r]);
        }
      }
    }
  }
}

// ---------------- MFMA flash attention (v5: AQT=128, 2 q-groups/wave) ---------
// Block = 4 waves, 128 Q-rows of one (b,h); each wave owns 2 groups of 16 q.
// Single-buffered K/V (6 blocks/CU LDS cap beats dbuf's 3 — measured R4).
// Each staged 64-KV tile is consumed by BOTH q-groups: staging/mask/barrier
// cost per unit work halves, MFMA density doubles.
// Swapped QK^T (mfma(K,Q)): lane owns one q-column, kv in register dim ->
// lane-local max/sum + 2 shfl_xor, scalar m/l/alpha, log2-domain exp.
// Ps (8KB) time-shared by the 2 groups: all P traffic is within-wave
// (wave writes/reads only rows wv*16..wv*16+15), in-order via lgkmcnt.
// LDS tiles [64][64] shorts, XOR swizzle col^=(row&7)<<3 (16B granules);
// K/V staged with PRE-SWIZZLED global source (m173 pattern), hoisted pointers.
// Og may alias Qg (both groups' Q frags register-resident before any write).
#define AQT 128
#define AKT 64
__global__ __launch_bounds__(256) void attn_mfma(
    const unsigned short* __restrict__ Qg,   // [B*S][D_MODEL] bf16
    const unsigned short* __restrict__ Kg,   // [B*S][D_MODEL] bf16
    const unsigned short* __restrict__ Vt,   // [(b*NH+h)*DK + d][SEQ] bf16 (transposed)
    const int* __restrict__ mask,            // [B*S]
    unsigned short* __restrict__ Og)
{
  __shared__ __attribute__((aligned(16))) short Ks[AKT * 64];
  __shared__ __attribute__((aligned(16))) short Vs[DK * 64];
  __shared__ __attribute__((aligned(16))) short Ps[64 * 64];
  __shared__ __attribute__((aligned(16))) float maddf[AKT];

  const int bid = blockIdx.x;
  const int nqt = SEQ / AQT;          // 16
  const int b  = bid / (NH * nqt);
  const int h  = (bid / nqt) % NH;
  const int q0 = (bid % nqt) * AQT;
  const int t  = threadIdx.x;
  const int wv = t >> 6, lane = t & 63;
  const int quad = lane >> 4, l15 = lane & 15;
  const int sw = (l15 & 7) << 3;      // shared XOR swizzle for all row&7==l15&7 reads
  const float SCL = 0.125f * 1.44269504f;   // score scale in log2 domain

  bf16x8 qf[2][2];
  #pragma unroll
  for (int g = 0; g < 2; g++) {
    const unsigned short* qrow =
        Qg + (size_t)(b * SEQ + q0 + g * 64 + wv * 16 + l15) * D_MODEL + h * DK;
    qf[g][0] = *(const bf16x8*)(qrow + quad * 8);
    qf[g][1] = *(const bf16x8*)(qrow + 32 + quad * 8);
  }
  f32x4 oacc[2][4] = {};
  float m_run[2] = { -1e30f, -1e30f };
  float l_run[2] = { 0.0f, 0.0f };

  // hoisted staging pointers: thread t covers rows (t>>3) and (t>>3)+32,
  // byte-col ((t&7)*8)^swizzle — same swizzle both halves ((row+32)&7 == row&7).
  const int srow = t >> 3;
  const int scol = ((t & 7) * 8) ^ ((srow & 7) << 3);
  const unsigned short* kp = Kg + (size_t)(b * SEQ + srow) * D_MODEL + h * DK + scol;
  const unsigned short* vp = Vt + ((size_t)(b * NH + h) * DK + srow) * SEQ + scol;
  const int* mp = mask + b * SEQ;
  const int prow = wv * 16 + l15;

  for (int kt = 0; kt < SEQ; kt += AKT) {
    gl_lds16(kp,                  &Ks[t * 8]);
    gl_lds16(kp + 32 * D_MODEL,   &Ks[(256 + t) * 8]);
    gl_lds16(vp,                  &Vs[t * 8]);
    gl_lds16(vp + 32 * SEQ,       &Vs[(256 + t) * 8]);
    if (t < AKT) maddf[t] = mp[t] ? 0.0f : -1.0e9f;
    __syncthreads();

    #pragma unroll
    for (int g = 0; g < 2; g++) {
      // swapped QK^T: out[m=kv=ct*16+quad*4+r][n=q=l15]; scores in log2 domain
      f32x4 sc[4];
      #pragma unroll
      for (int ct = 0; ct < 4; ct++) {
        const int krow = ct * 16 + l15;
        bf16x8 kb0 = *(const bf16x8*)&Ks[krow * 64 + ((quad * 8) ^ sw)];
        bf16x8 kb1 = *(const bf16x8*)&Ks[krow * 64 + ((32 + quad * 8) ^ sw)];
        f32x4 a = {};
        a = __builtin_amdgcn_mfma_f32_16x16x32_bf16(kb0, qf[g][0], a, 0, 0, 0);
        a = __builtin_amdgcn_mfma_f32_16x16x32_bf16(kb1, qf[g][1], a, 0, 0, 0);
        f32x4 md = *(const f32x4*)&maddf[ct * 16 + quad * 4];
        #pragma unroll
        for (int r = 0; r < 4; r++) a[r] = a[r] * SCL + md[r];
        sc[ct] = a;
      }

      // lane-local row max over 16 kv values, then combine the 4 quads
      float tmax = fmaxf(fmaxf(sc[0][0], sc[0][1]), fmaxf(sc[0][2], sc[0][3]));
      #pragma unroll
      for (int ct = 1; ct < 4; ct++)
        tmax = fmaxf(tmax, fmaxf(fmaxf(sc[ct][0], sc[ct][1]), fmaxf(sc[ct][2], sc[ct][3])));
      tmax = fmaxf(tmax, __shfl_xor(tmax, 16));
      tmax = fmaxf(tmax, __shfl_xor(tmax, 32));

      // defer-max (T13): only rescale when max grew by > 8 nats (11.54 in log2)
      if (!__all(tmax - m_run[g] <= 11.5415603f)) {
        float mn = fmaxf(m_run[g], tmax);
        float alpha = fexp2(m_run[g] - mn);
        m_run[g] = mn;
        l_run[g] *= alpha;
        float a4[4];
        #pragma unroll
        for (int r = 0; r < 4; r++) a4[r] = __shfl(alpha, quad * 4 + r);
        #pragma unroll
        for (int dt = 0; dt < 4; dt++)
          #pragma unroll
          for (int r = 0; r < 4; r++) oacc[g][dt][r] *= a4[r];
      }

      // P = 2^(S - m); packed bf16 store: 4x ds_write_b64 (P[q][kv], swizzled)
      float rs = 0.0f;
      #pragma unroll
      for (int ct = 0; ct < 4; ct++) {
        float p0 = fexp2(sc[ct][0] - m_run[g]);
        float p1 = fexp2(sc[ct][1] - m_run[g]);
        float p2 = fexp2(sc[ct][2] - m_run[g]);
        float p3 = fexp2(sc[ct][3] - m_run[g]);
        rs += (p0 + p1) + (p2 + p3);
        unsigned int lo, hi;
        asm("v_cvt_pk_bf16_f32 %0, %1, %2" : "=v"(lo) : "v"(p0), "v"(p1));
        asm("v_cvt_pk_bf16_f32 %0, %1, %2" : "=v"(hi) : "v"(p2), "v"(p3));
        int2 pv; pv.x = (int)lo; pv.y = (int)hi;
        *(int2*)&Ps[prow * 64 + ((ct * 16 + quad * 4) ^ sw)] = pv;
      }
      rs += __shfl_xor(rs, 16);
      rs += __shfl_xor(rs, 32);
      l_run[g] += rs;

      // PV: A = P[q][kv 8-contig] (own wave's rows), B = V[kv][d] from Vs[d][kv]
      bf16x8 pf0 = *(const bf16x8*)&Ps[prow * 64 + ((quad * 8) ^ sw)];
      bf16x8 pf1 = *(const bf16x8*)&Ps[prow * 64 + ((32 + quad * 8) ^ sw)];
      #pragma unroll
      for (int dt = 0; dt < 4; dt++) {
        const int vrow = dt * 16 + l15;
        bf16x8 vb0 = *(const bf16x8*)&Vs[vrow * 64 + ((quad * 8) ^ sw)];
        bf16x8 vb1 = *(const bf16x8*)&Vs[vrow * 64 + ((32 + quad * 8) ^ sw)];
        oacc[g][dt] = __builtin_amdgcn_mfma_f32_16x16x32_bf16(pf0, vb0, oacc[g][dt], 0, 0, 0);
        oacc[g][dt] = __builtin_amdgcn_mfma_f32_16x16x32_bf16(pf1, vb1, oacc[g][dt], 0, 0, 0);
      }
    }
    __syncthreads();
    kp += (size_t)AKT * D_MODEL; vp += AKT; mp += AKT;
  }

  // transport 1/l from lane-layout (q=l15) to C-layout (q=quad*4+r)
  #pragma unroll
  for (int g = 0; g < 2; g++) {
    float li = 1.0f / l_run[g];
    float linv4[4];
    #pragma unroll
    for (int r = 0; r < 4; r++) linv4[r] = __shfl(li, quad * 4 + r);
    #pragma unroll
    for (int dt = 0; dt < 4; dt++)
      #pragma unroll
      for (int r = 0; r < 4; r++)
        Og[(size_t)(b * SEQ + q0 + g * 64 + wv * 16 + quad * 4 + r) * D_MODEL + h * DK + dt * 16 + l15] =
          f2bf(oacc[g][dt][r] * linv4[r]);
  }
}

// ---------------- launch ----------------
// fp32 I/O. All GEMMs bf16 with just-in-time weight conversion. NO ws_size gate.
// ws high-water 48MB:
//   phase A: q [0,16)  k [16,32)  vt [32,48)
//   phase B (after attn): ao=q, wo16 -> [16,18) (k dead)
//   phase C (after o-proj): w1 -> [0,8), w2 -> [8,16) (ao dead); ln2 -> [32,48)
//            hff chunk -> [16,32)
// d_out as scratch: ln1b [0,16MB), wqkv16 [16,22MB); o-proj overwrites all with x1 fp32.
extern "C" void kernel_launch(void* const* d_in, const int* in_sizes, int n_in,
                              void* d_out, int out_size, void* d_ws, size_t ws_size,
                              hipStream_t stream)
{
  (void)in_sizes; (void)n_in; (void)out_size; (void)ws_size;
  const float* x   = (const float*)d_in[0];
  const int*   msk = (const int*)d_in[1];
  const float* w_q = (const float*)d_in[2];
  const float* w_k = (const float*)d_in[3];
  const float* w_v = (const float*)d_in[4];
  const float* w_o = (const float*)d_in[5];
  const float* w1  = (const float*)d_in[6];
  const float* b1  = (const float*)d_in[7];
  const float* w2  = (const float*)d_in[8];
  const float* b2  = (const float*)d_in[9];
  const float* g1  = (const float*)d_in[10];
  const float* be1 = (const float*)d_in[11];
  const float* g2  = (const float*)d_in[12];
  const float* be2 = (const float*)d_in[13];
  float* outf = (float*)d_out;

  char* ws = (char*)d_ws;
  const size_t MB = 1024 * 1024;
  unsigned short* q_b  = (unsigned short*)(ws + 0);        // 16MB -> ao
  unsigned short* k_b  = (unsigned short*)(ws + 16 * MB);  // 16MB -> wo16 -> hff chunk
  unsigned short* vt_b = (unsigned short*)(ws + 32 * MB);  // 16MB -> ln2b
  unsigned short* wo16 = (unsigned short*)(ws + 16 * MB);  // 2MB (k dead after attn)
  unsigned short* w116 = (unsigned short*)(ws + 0);        // 8MB (ao dead after o-proj)
  unsigned short* w216 = (unsigned short*)(ws + 8 * MB);   // 8MB
  unsigned short* ln2b = vt_b;                             // 16MB (vt dead after attn)
  unsigned short* hffc = k_b;                              // 16MB chunk

  unsigned short* ln1b   = (unsigned short*)d_out;                  // [0,16MB) of d_out
  unsigned short* wqkv16 = (unsigned short*)d_out + 8 * 1024 * 1024;// [16,22MB) of d_out

  dim3 blk(256);
  const int nw = D_MODEL * D_MODEL;  // 1M elems
  const int nf = DFF * D_MODEL;      // 4M elems

  // phase A: weights q|k|v -> fused bf16 [3072,1024] in d_out scratch; LN1
  cvt_f2b<<<nw / 1024, blk, 0, stream>>>(w_q, wqkv16, nw);
  cvt_f2b<<<nw / 1024, blk, 0, stream>>>(w_k, wqkv16 + nw, nw);
  cvt_f2b<<<nw / 1024, blk, 0, stream>>>(w_v, wqkv16 + 2 * nw, nw);
  ln_kernel<<<NROWS, blk, 0, stream>>>(x, g1, be1, ln1b);

  // fused QKV: [8192,1024] x [3072,1024]^T -> q, k, vt
  dim3 gqkv(3 * D_MODEL / 128, NROWS / 128);  // (24, 64) = 1536 blocks
  gemm_bt<<<gqkv, blk, 0, stream>>>(ln1b, wqkv16, D_MODEL, 3 * D_MODEL, D_MODEL, D_MODEL,
                                    nullptr, 0, nullptr, nullptr, nullptr, nullptr,
                                    q_b, k_b, vt_b);

  // attention (output in-place over q); AQT=128 -> 1024 blocks
  attn_mfma<<<BATCH * NH * (SEQ / AQT), blk, 0, stream>>>(q_b, k_b, vt_b, msk, q_b);

  // phase B: wo -> dead k region; o-proj + residual(x) -> x1 = d_out (fp32)
  cvt_f2b<<<nw / 1024, blk, 0, stream>>>(w_o, wo16, nw);
  dim3 gN1024(D_MODEL / 128, NROWS / 128);  // (8, 64)
  gemm_bt<<<gN1024, blk, 0, stream>>>(q_b, wo16, D_MODEL, D_MODEL, D_MODEL, D_MODEL,
                                      nullptr, 0, x, nullptr, outf, nullptr,
                                      nullptr, nullptr, nullptr);

  // phase C: w1/w2 -> dead ao region; LN2 -> dead vt region; chunked FFN
  cvt_f2b<<<nf / 1024, blk, 0, stream>>>(w1, w116, nf);
  cvt_f2b<<<nf / 1024, blk, 0, stream>>>(w2, w216, nf);
  ln_kernel<<<NROWS, blk, 0, stream>>>(outf, g2, be2, ln2b);
  for (int c = 0; c < NCHUNK; c++) {
    const size_t ro = (size_t)c * CHUNK;
    dim3 g1c(DFF / 128,     CHUNK / 128);      // (32, 16) = 512 blocks
    dim3 g2c(D_MODEL / 128, CHUNK / 128, 4);   // (8, 16, 4) = 512 blocks, split-K
    gemm_bt<<<g1c, blk, 0, stream>>>(ln2b + ro * D_MODEL, w116, D_MODEL, DFF,
                                     D_MODEL, D_MODEL, b1, 1,
                                     nullptr, hffc, nullptr, nullptr,
                                     nullptr, nullptr, nullptr);
    // FFN2 split-K=4 (K=1024 each): outf already holds x1 (residual) in place;
    // partials accumulate via device-scope fp32 atomics, bias from split 0.
    gemm_bt<<<g2c, blk, 0, stream>>>(hffc, w216, DFF / 4, D_MODEL, DFF, DFF, b2, 0,
                                     nullptr, nullptr, nullptr, outf + ro * D_MODEL,
                                     nullptr, nullptr, nullptr);
  }
}

// Round 7
// 704.772 us; speedup vs baseline: 1.5222x; 1.0034x over previous
//
#include <hip/hip_runtime.h>

#define D_MODEL 1024
#define NH 16
#define DK 64
#define DFF 4096
#define SEQ 2048
#define BATCH 4
#define NROWS (BATCH*SEQ)   // 8192
#define CHUNK 2048          // FFN row-chunk (16MB bf16 hidden fits dead k region)
#define NCHUNK (NROWS/CHUNK)

typedef short bf16x8 __attribute__((ext_vector_type(8)));
typedef float f32x4 __attribute__((ext_vector_type(4)));

__device__ __forceinline__ float bf2f(unsigned short u){
  union { float f; unsigned int i; } x; x.i = ((unsigned int)u) << 16; return x.f;
}
__device__ __forceinline__ unsigned short f2bf(float f){
  union { float f; unsigned int i; } x; x.f = f;
  unsigned int r = x.i + 0x7fffu + ((x.i >> 16) & 1u);
  return (unsigned short)(r >> 16);
}
__device__ __forceinline__ float fexp2(float x){
#if __has_builtin(__builtin_amdgcn_exp2f)
  return __builtin_amdgcn_exp2f(x);
#else
  return __exp2f(x);
#endif
}

// async global->LDS, 16B per lane (m97 pattern; LDS dest = wave base + lane*16)
__device__ __forceinline__ void gl_lds16(const void* g, void* l) {
  __builtin_amdgcn_global_load_lds((const __attribute__((address_space(1))) void*)g,
                                   (__attribute__((address_space(3))) void*)l, 16, 0, 0);
}

// ---------------- fp32 -> bf16 bulk convert (weights) ----------------
__global__ __launch_bounds__(256) void cvt_f2b(const float* __restrict__ in,
                                               unsigned short* __restrict__ out, int n)
{
  int i = (blockIdx.x * 256 + threadIdx.x) * 4;
  if (i < n) {
    float4 f = *(const float4*)(in + i);
    union { int2 v; unsigned short u[4]; } o;
    o.u[0] = f2bf(f.x); o.u[1] = f2bf(f.y); o.u[2] = f2bf(f.z); o.u[3] = f2bf(f.w);
    *(int2*)(out + i) = o.v;
  }
}

// ---------------- LayerNorm: fp32 in -> bf16 out, one block per row of 1024 ----
// torch variant: unbiased std (ddof=1), eps added to std (not var)
__global__ __launch_bounds__(256) void ln_kernel(const float* __restrict__ in,
    const float* __restrict__ gam, const float* __restrict__ bet,
    unsigned short* __restrict__ out)
{
  const int row = blockIdx.x, t = threadIdx.x;
  const int base = t * 4;
  float4 raw = *(const float4*)(in + (size_t)row * D_MODEL + base);
  float v[4] = { raw.x, raw.y, raw.z, raw.w };
  float s  = v[0] + v[1] + v[2] + v[3];
  float s2 = v[0]*v[0] + v[1]*v[1] + v[2]*v[2] + v[3]*v[3];
  #pragma unroll
  for (int off = 32; off > 0; off >>= 1) {
    s  += __shfl_down(s,  off);
    s2 += __shfl_down(s2, off);
  }
  __shared__ float red[10];
  const int wid = t >> 6, lane = t & 63;
  if (lane == 0) { red[wid] = s; red[4 + wid] = s2; }
  __syncthreads();
  if (t == 0) {
    float ts  = red[0] + red[1] + red[2] + red[3];
    float ts2 = red[4] + red[5] + red[6] + red[7];
    float mean = ts * (1.0f / D_MODEL);
    float var  = (ts2 - (float)D_MODEL * mean * mean) * (1.0f / (D_MODEL - 1));
    var = fmaxf(var, 0.0f);
    red[8] = mean;
    red[9] = 1.0f / (sqrtf(var) + 1e-6f);
  }
  __syncthreads();
  const float mean = red[8], inv = red[9];
  float4 g4 = *(const float4*)(gam + base);
  float4 b4 = *(const float4*)(bet + base);
  union { int2 v; unsigned short u[4]; } o;
  o.u[0] = f2bf(g4.x * (v[0] - mean) * inv + b4.x);
  o.u[1] = f2bf(g4.y * (v[1] - mean) * inv + b4.y);
  o.u[2] = f2bf(g4.z * (v[2] - mean) * inv + b4.z);
  o.u[3] = f2bf(g4.w * (v[3] - mean) * inv + b4.w);
  *(int2*)(out + (size_t)row * D_MODEL + base) = o.v;
}

// ---------------- GEMM: C[m,n] = sum_k A[m,k] * Bw[n,k]  (+ epilogue) ----------
// All-bf16 operands; 2-phase pipeline: prefetch K-step t+1 via global_load_lds
// into the ALTERNATE static LDS buffer BEFORE computing step t (T3-minimum).
// Staging pointers hoisted: per-thread pa/pb advance by 32 elems per stage
// (no 64-bit addr recompute per step). One __syncthreads per K-step.
// (R5-verified structure; counted-vmcnt raw-barrier variant shelved after
//  container failures — regime-gate says its payoff needs 8-phase anyway.)
// 128x128 tile, BK=32, 4 waves (2x2), each wave 64x64 via 4x4 mfma_16x16x32_bf16.
// QKV mode (outq!=null): N=3072 fused; col block 0->q, 1->k, 2->vt (transposed).
// Split-K mode (atomf!=null): grid.z = #splits, each handles K cols
//   [z*K, (z+1)*K); epilogue atomicAdd fp32 (bias by z==0 only).
//   Target must be pre-initialized (residual).
__global__ __launch_bounds__(256) void gemm_bt(
    const unsigned short* __restrict__ A,   // [M,*] bf16, row stride sA
    const unsigned short* __restrict__ Bw,  // [N,*] bf16, row stride sB
    int K, int N, int sA, int sB,
    const float* __restrict__ bias,    // [N] fp32 or null
    int relu,
    const float* __restrict__ residf,  // [M,N] fp32 or null
    unsigned short* __restrict__ outb, // [M,N] bf16 or null
    float* __restrict__ outf,          // [M,N] fp32 or null
    float* __restrict__ atomf,         // [M,N] fp32 atomic-accum or null
    unsigned short* __restrict__ outq, // fused-QKV q  [M,1024] or null
    unsigned short* __restrict__ outk, //           k  [M,1024]
    unsigned short* __restrict__ outvt)//           v^T [(b,h),d,s]
{
  __shared__ __attribute__((aligned(16))) short sA0[128 * 32];
  __shared__ __attribute__((aligned(16))) short sA1[128 * 32];
  __shared__ __attribute__((aligned(16))) short sB0[128 * 32];
  __shared__ __attribute__((aligned(16))) short sB1[128 * 32];
  const int t = threadIdx.x;
  const int tileN = blockIdx.x * 128;
  const int tileM = blockIdx.y * 128;
  const int kz = blockIdx.z;
  const size_t koff = (size_t)kz * K;
  const int wid = t >> 6, lane = t & 63;
  const int wM = (wid >> 1) * 64, wN = (wid & 1) * 64;
  const int quad = lane >> 4, lrow = lane & 15;

  f32x4 acc[4][4] = {};

  // hoisted staging pointers: thread t covers rows (t>>2) and (t>>2)+64, col (t&3)*8
  const unsigned short* pa = A  + (size_t)(tileM + (t >> 2)) * sA + koff + (t & 3) * 8;
  const unsigned short* pb = Bw + (size_t)(tileN + (t >> 2)) * sB + koff + (t & 3) * 8;
  const size_t a64 = (size_t)64 * sA, b64 = (size_t)64 * sB;

  auto stageTo = [&](short* dA, short* dB) {
    gl_lds16(pa,       dA + t * 8);
    gl_lds16(pa + a64, dA + (256 + t) * 8);
    gl_lds16(pb,       dB + t * 8);
    gl_lds16(pb + b64, dB + (256 + t) * 8);
    pa += 32; pb += 32;
  };
  auto compute = [&](const short* cA, const short* cB) {
    bf16x8 af[4], bfr[4];
    #pragma unroll
    for (int i = 0; i < 4; i++) {
      af[i]  = *(const bf16x8*)&cA[(wM + i * 16 + lrow) * 32 + quad * 8];
      bfr[i] = *(const bf16x8*)&cB[(wN + i * 16 + lrow) * 32 + quad * 8];
    }
    #pragma unroll
    for (int i = 0; i < 4; i++)
      #pragma unroll
      for (int j = 0; j < 4; j++)
        acc[i][j] = __builtin_amdgcn_mfma_f32_16x16x32_bf16(af[i], bfr[j], acc[i][j], 0, 0, 0);
  };

  const int nk = K >> 5;                 // always even for our shapes
  stageTo(sA0, sB0);
  __syncthreads();
  for (int ik = 0; ik < nk; ik += 2) {
    if (ik + 1 < nk) stageTo(sA1, sB1);
    compute(sA0, sB0);
    __syncthreads();
    if (ik + 2 < nk) stageTo(sA0, sB0);
    compute(sA1, sB1);
    __syncthreads();
  }

  // fused-QKV epilogue target for this block (tileN is 128-aligned; one cat/block)
  unsigned short* qk_out = nullptr;
  int qkv_cat = 0;
  if (outq) {
    qkv_cat = tileN >> 10;                 // 0=q 1=k 2=v
    qk_out = (qkv_cat == 0) ? outq : outk;
  }

  #pragma unroll
  for (int i = 0; i < 4; i++) {
    #pragma unroll
    for (int j = 0; j < 4; j++) {
      const int col  = tileN + wN + j * 16 + lrow;
      const int row0 = tileM + wM + i * 16 + quad * 4;
      const float bv = (bias && kz == 0) ? bias[col] : 0.0f;
      float vals[4];
      #pragma unroll
      for (int r = 0; r < 4; r++) {
        float val = acc[i][j][r] + bv;
        if (relu) val = fmaxf(val, 0.0f);
        if (residf) val += residf[(size_t)(row0 + r) * N + col];
        vals[r] = val;
      }
      if (outq) {
        const int lcol = col & 1023;
        if (qkv_cat < 2) {
          #pragma unroll
          for (int r = 0; r < 4; r++)
            qk_out[(size_t)(row0 + r) * D_MODEL + lcol] = f2bf(vals[r]);
        } else {
          // vt[((b*NH+h)*DK+d)*SEQ + s]: b=row>>11, s=row&2047, h=lcol>>6, d=lcol&63
          union { int2 v; unsigned short u[4]; } pk;
          #pragma unroll
          for (int r = 0; r < 4; r++) pk.u[r] = f2bf(vals[r]);
          size_t tidx = (((size_t)(row0 >> 11) * NH + (lcol >> 6)) * DK + (lcol & 63)) * SEQ + (row0 & 2047);
          *(int2*)(outvt + tidx) = pk.v;
        }
      } else if (atomf) {
        #pragma unroll
        for (int r = 0; r < 4; r++)
          atomicAdd(&atomf[(size_t)(row0 + r) * N + col], vals[r]);
      } else {
        #pragma unroll
        for (int r = 0; r < 4; r++) {
          const size_t idx = (size_t)(row0 + r) * N + col;
          if (outf) outf[idx] = vals[r];
          if (outb) outb[idx] = f2bf(vals[r]);
        }
      }
    }
  }
}

// ---------------- MFMA flash attention (v6: T15 two-group pipeline) -----------
// Block = 4 waves, 128 Q-rows of one (b,h); each wave owns 2 groups of 16 q.
// Per tile, phase-split so the two groups' chains overlap:
//   P1: QK(g0)+QK(g1) back-to-back, SHARED K fragment loads (8 ds_read not 16)
//   P2: softmax g0 -> Ps0; softmax g1 -> Ps1 (separate buffers = no serialization)
//   P3: PV(g0)+PV(g1), SHARED V fragment loads (8 ds_read not 16)
// g1's QK MFMAs issue while g0's results drain; softmax VALU overlaps matrix pipe.
// Swapped QK^T (mfma(K,Q)): lane owns one q-column, kv in register dim ->
// lane-local max/sum + 2 shfl_xor, scalar m/l/alpha, log2-domain exp.
// LDS tiles [64][64] shorts, XOR swizzle col^=(row&7)<<3 (16B granules);
// K/V staged with PRE-SWIZZLED global source (m173 pattern), hoisted pointers.
// LDS total ~33KB -> 4 blocks/CU = exactly the grid's 4/CU residency.
// Og may alias Qg (both groups' Q frags register-resident before any write).
#define AQT 128
#define AKT 64
__global__ __launch_bounds__(256) void attn_mfma(
    const unsigned short* __restrict__ Qg,   // [B*S][D_MODEL] bf16
    const unsigned short* __restrict__ Kg,   // [B*S][D_MODEL] bf16
    const unsigned short* __restrict__ Vt,   // [(b*NH+h)*DK + d][SEQ] bf16 (transposed)
    const int* __restrict__ mask,            // [B*S]
    unsigned short* __restrict__ Og)
{
  __shared__ __attribute__((aligned(16))) short Ks[AKT * 64];
  __shared__ __attribute__((aligned(16))) short Vs[DK * 64];
  __shared__ __attribute__((aligned(16))) short Ps0[64 * 64];
  __shared__ __attribute__((aligned(16))) short Ps1[64 * 64];
  __shared__ __attribute__((aligned(16))) float maddf[AKT];

  const int bid = blockIdx.x;
  const int nqt = SEQ / AQT;          // 16
  const int b  = bid / (NH * nqt);
  const int h  = (bid / nqt) % NH;
  const int q0 = (bid % nqt) * AQT;
  const int t  = threadIdx.x;
  const int wv = t >> 6, lane = t & 63;
  const int quad = lane >> 4, l15 = lane & 15;
  const int sw = (l15 & 7) << 3;      // shared XOR swizzle for all row&7==l15&7 reads
  const float SCL = 0.125f * 1.44269504f;   // score scale in log2 domain

  bf16x8 qf[2][2];
  #pragma unroll
  for (int g = 0; g < 2; g++) {
    const unsigned short* qrow =
        Qg + (size_t)(b * SEQ + q0 + g * 64 + wv * 16 + l15) * D_MODEL + h * DK;
    qf[g][0] = *(const bf16x8*)(qrow + quad * 8);
    qf[g][1] = *(const bf16x8*)(qrow + 32 + quad * 8);
  }
  f32x4 oacc[2][4] = {};
  float m_run[2] = { -1e30f, -1e30f };
  float l_run[2] = { 0.0f, 0.0f };

  // hoisted staging pointers: thread t covers rows (t>>3) and (t>>3)+32,
  // byte-col ((t&7)*8)^swizzle — same swizzle both halves ((row+32)&7 == row&7).
  const int srow = t >> 3;
  const int scol = ((t & 7) * 8) ^ ((srow & 7) << 3);
  const unsigned short* kp = Kg + (size_t)(b * SEQ + srow) * D_MODEL + h * DK + scol;
  const unsigned short* vp = Vt + ((size_t)(b * NH + h) * DK + srow) * SEQ + scol;
  const int* mp = mask + b * SEQ;
  const int prow = wv * 16 + l15;

  for (int kt = 0; kt < SEQ; kt += AKT) {
    gl_lds16(kp,                  &Ks[t * 8]);
    gl_lds16(kp + 32 * D_MODEL,   &Ks[(256 + t) * 8]);
    gl_lds16(vp,                  &Vs[t * 8]);
    gl_lds16(vp + 32 * SEQ,       &Vs[(256 + t) * 8]);
    if (t < AKT) maddf[t] = mp[t] ? 0.0f : -1.0e9f;
    __syncthreads();

    // ---- P1: QK^T both groups, shared K frags; scores in log2 domain ----
    f32x4 sc[2][4];
    #pragma unroll
    for (int ct = 0; ct < 4; ct++) {
      const int krow = ct * 16 + l15;
      bf16x8 kb0 = *(const bf16x8*)&Ks[krow * 64 + ((quad * 8) ^ sw)];
      bf16x8 kb1 = *(const bf16x8*)&Ks[krow * 64 + ((32 + quad * 8) ^ sw)];
      f32x4 a0 = {}, a1 = {};
      a0 = __builtin_amdgcn_mfma_f32_16x16x32_bf16(kb0, qf[0][0], a0, 0, 0, 0);
      a0 = __builtin_amdgcn_mfma_f32_16x16x32_bf16(kb1, qf[0][1], a0, 0, 0, 0);
      a1 = __builtin_amdgcn_mfma_f32_16x16x32_bf16(kb0, qf[1][0], a1, 0, 0, 0);
      a1 = __builtin_amdgcn_mfma_f32_16x16x32_bf16(kb1, qf[1][1], a1, 0, 0, 0);
      f32x4 md = *(const f32x4*)&maddf[ct * 16 + quad * 4];
      #pragma unroll
      for (int r = 0; r < 4; r++) {
        a0[r] = a0[r] * SCL + md[r];
        a1[r] = a1[r] * SCL + md[r];
      }
      sc[0][ct] = a0; sc[1][ct] = a1;
    }

    // ---- P2: softmax per group into its OWN P buffer ----
    #pragma unroll
    for (int g = 0; g < 2; g++) {
      short* Pg = g ? Ps1 : Ps0;
      float tmax = fmaxf(fmaxf(sc[g][0][0], sc[g][0][1]), fmaxf(sc[g][0][2], sc[g][0][3]));
      #pragma unroll
      for (int ct = 1; ct < 4; ct++)
        tmax = fmaxf(tmax, fmaxf(fmaxf(sc[g][ct][0], sc[g][ct][1]),
                                 fmaxf(sc[g][ct][2], sc[g][ct][3])));
      tmax = fmaxf(tmax, __shfl_xor(tmax, 16));
      tmax = fmaxf(tmax, __shfl_xor(tmax, 32));

      // defer-max (T13): only rescale when max grew by > 8 nats (11.54 in log2)
      if (!__all(tmax - m_run[g] <= 11.5415603f)) {
        float mn = fmaxf(m_run[g], tmax);
        float alpha = fexp2(m_run[g] - mn);
        m_run[g] = mn;
        l_run[g] *= alpha;
        float a4[4];
        #pragma unroll
        for (int r = 0; r < 4; r++) a4[r] = __shfl(alpha, quad * 4 + r);
        #pragma unroll
        for (int dt = 0; dt < 4; dt++)
          #pragma unroll
          for (int r = 0; r < 4; r++) oacc[g][dt][r] *= a4[r];
      }

      // P = 2^(S - m); packed bf16 store: 4x ds_write_b64 (P[q][kv], swizzled)
      float rs = 0.0f;
      #pragma unroll
      for (int ct = 0; ct < 4; ct++) {
        float p0 = fexp2(sc[g][ct][0] - m_run[g]);
        float p1 = fexp2(sc[g][ct][1] - m_run[g]);
        float p2 = fexp2(sc[g][ct][2] - m_run[g]);
        float p3 = fexp2(sc[g][ct][3] - m_run[g]);
        rs += (p0 + p1) + (p2 + p3);
        unsigned int lo, hi;
        asm("v_cvt_pk_bf16_f32 %0, %1, %2" : "=v"(lo) : "v"(p0), "v"(p1));
        asm("v_cvt_pk_bf16_f32 %0, %1, %2" : "=v"(hi) : "v"(p2), "v"(p3));
        int2 pv; pv.x = (int)lo; pv.y = (int)hi;
        *(int2*)&Pg[prow * 64 + ((ct * 16 + quad * 4) ^ sw)] = pv;
      }
      rs += __shfl_xor(rs, 16);
      rs += __shfl_xor(rs, 32);
      l_run[g] += rs;
    }

    // ---- P3: PV both groups, shared V frags ----
    bf16x8 pf00 = *(const bf16x8*)&Ps0[prow * 64 + ((quad * 8) ^ sw)];
    bf16x8 pf01 = *(const bf16x8*)&Ps0[prow * 64 + ((32 + quad * 8) ^ sw)];
    bf16x8 pf10 = *(const bf16x8*)&Ps1[prow * 64 + ((quad * 8) ^ sw)];
    bf16x8 pf11 = *(const bf16x8*)&Ps1[prow * 64 + ((32 + quad * 8) ^ sw)];
    #pragma unroll
    for (int dt = 0; dt < 4; dt++) {
      const int vrow = dt * 16 + l15;
      bf16x8 vb0 = *(const bf16x8*)&Vs[vrow * 64 + ((quad * 8) ^ sw)];
      bf16x8 vb1 = *(const bf16x8*)&Vs[vrow * 64 + ((32 + quad * 8) ^ sw)];
      oacc[0][dt] = __builtin_amdgcn_mfma_f32_16x16x32_bf16(pf00, vb0, oacc[0][dt], 0, 0, 0);
      oacc[0][dt] = __builtin_amdgcn_mfma_f32_16x16x32_bf16(pf01, vb1, oacc[0][dt], 0, 0, 0);
      oacc[1][dt] = __builtin_amdgcn_mfma_f32_16x16x32_bf16(pf10, vb0, oacc[1][dt], 0, 0, 0);
      oacc[1][dt] = __builtin_amdgcn_mfma_f32_16x16x32_bf16(pf11, vb1, oacc[1][dt], 0, 0, 0);
    }
    __syncthreads();
    kp += (size_t)AKT * D_MODEL; vp += AKT; mp += AKT;
  }

  // transport 1/l from lane-layout (q=l15) to C-layout (q=quad*4+r)
  #pragma unroll
  for (int g = 0; g < 2; g++) {
    float li = 1.0f / l_run[g];
    float linv4[4];
    #pragma unroll
    for (int r = 0; r < 4; r++) linv4[r] = __shfl(li, quad * 4 + r);
    #pragma unroll
    for (int dt = 0; dt < 4; dt++)
      #pragma unroll
      for (int r = 0; r < 4; r++)
        Og[(size_t)(b * SEQ + q0 + g * 64 + wv * 16 + quad * 4 + r) * D_MODEL + h * DK + dt * 16 + l15] =
          f2bf(oacc[g][dt][r] * linv4[r]);
  }
}

// ---------------- launch ----------------
// fp32 I/O. All GEMMs bf16 with just-in-time weight conversion. NO ws_size gate.
// ws high-water 48MB:
//   phase A: q [0,16)  k [16,32)  vt [32,48)
//   phase B (after attn): ao=q, wo16 -> [16,18) (k dead)
//   phase C (after o-proj): w1 -> [0,8), w2 -> [8,16) (ao dead); ln2 -> [32,48)
//            hff chunk -> [16,32)
// d_out as scratch: ln1b [0,16MB), wqkv16 [16,22MB); o-proj overwrites all with x1 fp32.
extern "C" void kernel_launch(void* const* d_in, const int* in_sizes, int n_in,
                              void* d_out, int out_size, void* d_ws, size_t ws_size,
                              hipStream_t stream)
{
  (void)in_sizes; (void)n_in; (void)out_size; (void)ws_size;
  const float* x   = (const float*)d_in[0];
  const int*   msk = (const int*)d_in[1];
  const float* w_q = (const float*)d_in[2];
  const float* w_k = (const float*)d_in[3];
  const float* w_v = (const float*)d_in[4];
  const float* w_o = (const float*)d_in[5];
  const float* w1  = (const float*)d_in[6];
  const float* b1  = (const float*)d_in[7];
  const float* w2  = (const float*)d_in[8];
  const float* b2  = (const float*)d_in[9];
  const float* g1  = (const float*)d_in[10];
  const float* be1 = (const float*)d_in[11];
  const float* g2  = (const float*)d_in[12];
  const float* be2 = (const float*)d_in[13];
  float* outf = (float*)d_out;

  char* ws = (char*)d_ws;
  const size_t MB = 1024 * 1024;
  unsigned short* q_b  = (unsigned short*)(ws + 0);        // 16MB -> ao
  unsigned short* k_b  = (unsigned short*)(ws + 16 * MB);  // 16MB -> wo16 -> hff chunk
  unsigned short* vt_b = (unsigned short*)(ws + 32 * MB);  // 16MB -> ln2b
  unsigned short* wo16 = (unsigned short*)(ws + 16 * MB);  // 2MB (k dead after attn)
  unsigned short* w116 = (unsigned short*)(ws + 0);        // 8MB (ao dead after o-proj)
  unsigned short* w216 = (unsigned short*)(ws + 8 * MB);   // 8MB
  unsigned short* ln2b = vt_b;                             // 16MB (vt dead after attn)
  unsigned short* hffc = k_b;                              // 16MB chunk

  unsigned short* ln1b   = (unsigned short*)d_out;                  // [0,16MB) of d_out
  unsigned short* wqkv16 = (unsigned short*)d_out + 8 * 1024 * 1024;// [16,22MB) of d_out

  dim3 blk(256);
  const int nw = D_MODEL * D_MODEL;  // 1M elems
  const int nf = DFF * D_MODEL;      // 4M elems

  // phase A: weights q|k|v -> fused bf16 [3072,1024] in d_out scratch; LN1
  cvt_f2b<<<nw / 1024, blk, 0, stream>>>(w_q, wqkv16, nw);
  cvt_f2b<<<nw / 1024, blk, 0, stream>>>(w_k, wqkv16 + nw, nw);
  cvt_f2b<<<nw / 1024, blk, 0, stream>>>(w_v, wqkv16 + 2 * nw, nw);
  ln_kernel<<<NROWS, blk, 0, stream>>>(x, g1, be1, ln1b);

  // fused QKV: [8192,1024] x [3072,1024]^T -> q, k, vt
  dim3 gqkv(3 * D_MODEL / 128, NROWS / 128);  // (24, 64) = 1536 blocks
  gemm_bt<<<gqkv, blk, 0, stream>>>(ln1b, wqkv16, D_MODEL, 3 * D_MODEL, D_MODEL, D_MODEL,
                                    nullptr, 0, nullptr, nullptr, nullptr, nullptr,
                                    q_b, k_b, vt_b);

  // attention (output in-place over q); AQT=128 -> 1024 blocks
  attn_mfma<<<BATCH * NH * (SEQ / AQT), blk, 0, stream>>>(q_b, k_b, vt_b, msk, q_b);

  // phase B: wo -> dead k region; o-proj + residual(x) -> x1 = d_out (fp32)
  cvt_f2b<<<nw / 1024, blk, 0, stream>>>(w_o, wo16, nw);
  dim3 gN1024(D_MODEL / 128, NROWS / 128);  // (8, 64)
  gemm_bt<<<gN1024, blk, 0, stream>>>(q_b, wo16, D_MODEL, D_MODEL, D_MODEL, D_MODEL,
                                      nullptr, 0, x, nullptr, outf, nullptr,
                                      nullptr, nullptr, nullptr);

  // phase C: w1/w2 -> dead ao region; LN2 -> dead vt region; chunked FFN
  cvt_f2b<<<nf / 1024, blk, 0, stream>>>(w1, w116, nf);
  cvt_f2b<<<nf / 1024, blk, 0, stream>>>(w2, w216, nf);
  ln_kernel<<<NROWS, blk, 0, stream>>>(outf, g2, be2, ln2b);
  for (int c = 0; c < NCHUNK; c++) {
    const size_t ro = (size_t)c * CHUNK;
    dim3 g1c(DFF / 128,     CHUNK / 128);      // (32, 16) = 512 blocks
    dim3 g2c(D_MODEL / 128, CHUNK / 128, 4);   // (8, 16, 4) = 512 blocks, split-K
    gemm_bt<<<g1c, blk, 0, stream>>>(ln2b + ro * D_MODEL, w116, D_MODEL, DFF,
                                     D_MODEL, D_MODEL, b1, 1,
                                     nullptr, hffc, nullptr, nullptr,
                                     nullptr, nullptr, nullptr);
    // FFN2 split-K=4 (K=1024 each): outf already holds x1 (residual) in place;
    // partials accumulate via device-scope fp32 atomics, bias from split 0.
    gemm_bt<<<g2c, blk, 0, stream>>>(hffc, w216, DFF / 4, D_MODEL, DFF, DFF, b2, 0,
                                     nullptr, nullptr, nullptr, outf + ro * D_MODEL,
                                     nullptr, nullptr, nullptr);
  }
}

// Round 8
// 699.043 us; speedup vs baseline: 1.5347x; 1.0082x over previous
//
#include <hip/hip_runtime.h>

#define D_MODEL 1024
#define NH 16
#define DK 64
#define DFF 4096
#define SEQ 2048
#define BATCH 4
#define NROWS (BATCH*SEQ)   // 8192
#define CHUNK 2048          // FFN row-chunk (16MB bf16 hidden fits dead k region)
#define NCHUNK (NROWS/CHUNK)

typedef short bf16x8 __attribute__((ext_vector_type(8)));
typedef float f32x4 __attribute__((ext_vector_type(4)));

__device__ __forceinline__ float bf2f(unsigned short u){
  union { float f; unsigned int i; } x; x.i = ((unsigned int)u) << 16; return x.f;
}
__device__ __forceinline__ unsigned short f2bf(float f){
  union { float f; unsigned int i; } x; x.f = f;
  unsigned int r = x.i + 0x7fffu + ((x.i >> 16) & 1u);
  return (unsigned short)(r >> 16);
}
__device__ __forceinline__ float fexp2(float x){
#if __has_builtin(__builtin_amdgcn_exp2f)
  return __builtin_amdgcn_exp2f(x);
#else
  return __exp2f(x);
#endif
}

// async global->LDS, 16B per lane (m97 pattern; LDS dest = wave base + lane*16)
__device__ __forceinline__ void gl_lds16(const void* g, void* l) {
  __builtin_amdgcn_global_load_lds((const __attribute__((address_space(1))) void*)g,
                                   (__attribute__((address_space(3))) void*)l, 16, 0, 0);
}

// T1 XCD-aware swizzle: hardware block hid lands on XCD hid%8; remap so each
// XCD gets a CONTIGUOUS logical chunk -> blocks sharing operand panels hit the
// same per-XCD L2. Bijective iff total % 8 == 0 (true at every call site).
__device__ __forceinline__ int xcd_swz(int hid, int total) {
  return (hid & 7) * (total >> 3) + (hid >> 3);
}

// ---------------- fp32 -> bf16 bulk convert (weights) ----------------
__global__ __launch_bounds__(256) void cvt_f2b(const float* __restrict__ in,
                                               unsigned short* __restrict__ out, int n)
{
  int i = (blockIdx.x * 256 + threadIdx.x) * 4;
  if (i < n) {
    float4 f = *(const float4*)(in + i);
    union { int2 v; unsigned short u[4]; } o;
    o.u[0] = f2bf(f.x); o.u[1] = f2bf(f.y); o.u[2] = f2bf(f.z); o.u[3] = f2bf(f.w);
    *(int2*)(out + i) = o.v;
  }
}

// ---------------- LayerNorm: fp32 in -> bf16 out, one block per row of 1024 ----
// torch variant: unbiased std (ddof=1), eps added to std (not var)
__global__ __launch_bounds__(256) void ln_kernel(const float* __restrict__ in,
    const float* __restrict__ gam, const float* __restrict__ bet,
    unsigned short* __restrict__ out)
{
  const int row = blockIdx.x, t = threadIdx.x;
  const int base = t * 4;
  float4 raw = *(const float4*)(in + (size_t)row * D_MODEL + base);
  float v[4] = { raw.x, raw.y, raw.z, raw.w };
  float s  = v[0] + v[1] + v[2] + v[3];
  float s2 = v[0]*v[0] + v[1]*v[1] + v[2]*v[2] + v[3]*v[3];
  #pragma unroll
  for (int off = 32; off > 0; off >>= 1) {
    s  += __shfl_down(s,  off);
    s2 += __shfl_down(s2, off);
  }
  __shared__ float red[10];
  const int wid = t >> 6, lane = t & 63;
  if (lane == 0) { red[wid] = s; red[4 + wid] = s2; }
  __syncthreads();
  if (t == 0) {
    float ts  = red[0] + red[1] + red[2] + red[3];
    float ts2 = red[4] + red[5] + red[6] + red[7];
    float mean = ts * (1.0f / D_MODEL);
    float var  = (ts2 - (float)D_MODEL * mean * mean) * (1.0f / (D_MODEL - 1));
    var = fmaxf(var, 0.0f);
    red[8] = mean;
    red[9] = 1.0f / (sqrtf(var) + 1e-6f);
  }
  __syncthreads();
  const float mean = red[8], inv = red[9];
  float4 g4 = *(const float4*)(gam + base);
  float4 b4 = *(const float4*)(bet + base);
  union { int2 v; unsigned short u[4]; } o;
  o.u[0] = f2bf(g4.x * (v[0] - mean) * inv + b4.x);
  o.u[1] = f2bf(g4.y * (v[1] - mean) * inv + b4.y);
  o.u[2] = f2bf(g4.z * (v[2] - mean) * inv + b4.z);
  o.u[3] = f2bf(g4.w * (v[3] - mean) * inv + b4.w);
  *(int2*)(out + (size_t)row * D_MODEL + base) = o.v;
}

// ---------------- GEMM: C[m,n] = sum_k A[m,k] * Bw[n,k]  (+ epilogue) ----------
// All-bf16 operands; 2-phase pipeline: prefetch K-step t+1 via global_load_lds
// into the ALTERNATE static LDS buffer BEFORE computing step t (T3-minimum).
// Staging pointers hoisted. One __syncthreads per K-step.
// T1 XCD swizzle on the (x,y) block id: consecutive logical blocks (sharing
// the A-panel) stay on one XCD's L2.
// 128x128 tile, BK=32, 4 waves (2x2), each wave 64x64 via 4x4 mfma_16x16x32_bf16.
// QKV mode (outq!=null): N=3072 fused; col block 0->q, 1->k, 2->vt (transposed).
// Split-K mode (atomf!=null): grid.z = #splits, each handles K cols
//   [z*K, (z+1)*K); epilogue atomicAdd fp32 (bias by z==0 only).
//   Target must be pre-initialized (residual).
__global__ __launch_bounds__(256) void gemm_bt(
    const unsigned short* __restrict__ A,   // [M,*] bf16, row stride sA
    const unsigned short* __restrict__ Bw,  // [N,*] bf16, row stride sB
    int K, int N, int sA, int sB,
    const float* __restrict__ bias,    // [N] fp32 or null
    int relu,
    const float* __restrict__ residf,  // [M,N] fp32 or null
    unsigned short* __restrict__ outb, // [M,N] bf16 or null
    float* __restrict__ outf,          // [M,N] fp32 or null
    float* __restrict__ atomf,         // [M,N] fp32 atomic-accum or null
    unsigned short* __restrict__ outq, // fused-QKV q  [M,1024] or null
    unsigned short* __restrict__ outk, //           k  [M,1024]
    unsigned short* __restrict__ outvt)//           v^T [(b,h),d,s]
{
  __shared__ __attribute__((aligned(16))) short sA0[128 * 32];
  __shared__ __attribute__((aligned(16))) short sA1[128 * 32];
  __shared__ __attribute__((aligned(16))) short sB0[128 * 32];
  __shared__ __attribute__((aligned(16))) short sB1[128 * 32];
  const int t = threadIdx.x;
  // T1: swizzle (x,y)-linearized block id (total always % 8 == 0 here)
  const int lid  = xcd_swz(blockIdx.y * gridDim.x + blockIdx.x,
                           gridDim.x * gridDim.y);
  const int tileN = (lid % gridDim.x) * 128;
  const int tileM = (lid / gridDim.x) * 128;
  const int kz = blockIdx.z;
  const size_t koff = (size_t)kz * K;
  const int wid = t >> 6, lane = t & 63;
  const int wM = (wid >> 1) * 64, wN = (wid & 1) * 64;
  const int quad = lane >> 4, lrow = lane & 15;

  f32x4 acc[4][4] = {};

  // hoisted staging pointers: thread t covers rows (t>>2) and (t>>2)+64, col (t&3)*8
  const unsigned short* pa = A  + (size_t)(tileM + (t >> 2)) * sA + koff + (t & 3) * 8;
  const unsigned short* pb = Bw + (size_t)(tileN + (t >> 2)) * sB + koff + (t & 3) * 8;
  const size_t a64 = (size_t)64 * sA, b64 = (size_t)64 * sB;

  auto stageTo = [&](short* dA, short* dB) {
    gl_lds16(pa,       dA + t * 8);
    gl_lds16(pa + a64, dA + (256 + t) * 8);
    gl_lds16(pb,       dB + t * 8);
    gl_lds16(pb + b64, dB + (256 + t) * 8);
    pa += 32; pb += 32;
  };
  auto compute = [&](const short* cA, const short* cB) {
    bf16x8 af[4], bfr[4];
    #pragma unroll
    for (int i = 0; i < 4; i++) {
      af[i]  = *(const bf16x8*)&cA[(wM + i * 16 + lrow) * 32 + quad * 8];
      bfr[i] = *(const bf16x8*)&cB[(wN + i * 16 + lrow) * 32 + quad * 8];
    }
    #pragma unroll
    for (int i = 0; i < 4; i++)
      #pragma unroll
      for (int j = 0; j < 4; j++)
        acc[i][j] = __builtin_amdgcn_mfma_f32_16x16x32_bf16(af[i], bfr[j], acc[i][j], 0, 0, 0);
  };

  const int nk = K >> 5;                 // always even for our shapes
  stageTo(sA0, sB0);
  __syncthreads();
  for (int ik = 0; ik < nk; ik += 2) {
    if (ik + 1 < nk) stageTo(sA1, sB1);
    compute(sA0, sB0);
    __syncthreads();
    if (ik + 2 < nk) stageTo(sA0, sB0);
    compute(sA1, sB1);
    __syncthreads();
  }

  // fused-QKV epilogue target for this block (tileN is 128-aligned; one cat/block)
  unsigned short* qk_out = nullptr;
  int qkv_cat = 0;
  if (outq) {
    qkv_cat = tileN >> 10;                 // 0=q 1=k 2=v
    qk_out = (qkv_cat == 0) ? outq : outk;
  }

  #pragma unroll
  for (int i = 0; i < 4; i++) {
    #pragma unroll
    for (int j = 0; j < 4; j++) {
      const int col  = tileN + wN + j * 16 + lrow;
      const int row0 = tileM + wM + i * 16 + quad * 4;
      const float bv = (bias && kz == 0) ? bias[col] : 0.0f;
      float vals[4];
      #pragma unroll
      for (int r = 0; r < 4; r++) {
        float val = acc[i][j][r] + bv;
        if (relu) val = fmaxf(val, 0.0f);
        if (residf) val += residf[(size_t)(row0 + r) * N + col];
        vals[r] = val;
      }
      if (outq) {
        const int lcol = col & 1023;
        if (qkv_cat < 2) {
          #pragma unroll
          for (int r = 0; r < 4; r++)
            qk_out[(size_t)(row0 + r) * D_MODEL + lcol] = f2bf(vals[r]);
        } else {
          // vt[((b*NH+h)*DK+d)*SEQ + s]: b=row>>11, s=row&2047, h=lcol>>6, d=lcol&63
          union { int2 v; unsigned short u[4]; } pk;
          #pragma unroll
          for (int r = 0; r < 4; r++) pk.u[r] = f2bf(vals[r]);
          size_t tidx = (((size_t)(row0 >> 11) * NH + (lcol >> 6)) * DK + (lcol & 63)) * SEQ + (row0 & 2047);
          *(int2*)(outvt + tidx) = pk.v;
        }
      } else if (atomf) {
        #pragma unroll
        for (int r = 0; r < 4; r++)
          atomicAdd(&atomf[(size_t)(row0 + r) * N + col], vals[r]);
      } else {
        #pragma unroll
        for (int r = 0; r < 4; r++) {
          const size_t idx = (size_t)(row0 + r) * N + col;
          if (outf) outf[idx] = vals[r];
          if (outb) outb[idx] = f2bf(vals[r]);
        }
      }
    }
  }
}

// ---------------- MFMA flash attention (v7: v6 + T1 XCD swizzle) --------------
// Block = 4 waves, 128 Q-rows of one (b,h); each wave owns 2 groups of 16 q.
// T1: 1024 blocks swizzled so the 16 q-tile blocks sharing one (b,h)'s 512KB
// K/V panel land on the SAME XCD -> K/V fetched from HBM once per XCD, not 8x.
// (R0-R7 invariant: FETCH_SIZE ~139MB vs ~64MB unique; dur == bytes/achieved-BW
//  across five compute restructures -> attn is fetch-bound, not compute-bound.)
// Per tile, phase-split (T15): QK both groups w/ shared K frags; softmax to
// Ps0/Ps1; PV both groups w/ shared V frags. Swapped QK^T, log2-domain softmax,
// defer-max; LDS [64][64] XOR-swizzled; gl_lds16 with pre-swizzled source.
// Og may alias Qg (both groups' Q frags register-resident before any write).
#define AQT 128
#define AKT 64
__global__ __launch_bounds__(256) void attn_mfma(
    const unsigned short* __restrict__ Qg,   // [B*S][D_MODEL] bf16
    const unsigned short* __restrict__ Kg,   // [B*S][D_MODEL] bf16
    const unsigned short* __restrict__ Vt,   // [(b*NH+h)*DK + d][SEQ] bf16 (transposed)
    const int* __restrict__ mask,            // [B*S]
    unsigned short* __restrict__ Og)
{
  __shared__ __attribute__((aligned(16))) short Ks[AKT * 64];
  __shared__ __attribute__((aligned(16))) short Vs[DK * 64];
  __shared__ __attribute__((aligned(16))) short Ps0[64 * 64];
  __shared__ __attribute__((aligned(16))) short Ps1[64 * 64];
  __shared__ __attribute__((aligned(16))) float maddf[AKT];

  // T1: swizzled logical id; q-tile is the fastest-varying field, so each XCD
  // owns contiguous q-tiles = whole (b,h) groups (1024/8 = 128 = 8 groups).
  const int bid = xcd_swz(blockIdx.x, gridDim.x);
  const int nqt = SEQ / AQT;          // 16
  const int b  = bid / (NH * nqt);
  const int h  = (bid / nqt) % NH;
  const int q0 = (bid % nqt) * AQT;
  const int t  = threadIdx.x;
  const int wv = t >> 6, lane = t & 63;
  const int quad = lane >> 4, l15 = lane & 15;
  const int sw = (l15 & 7) << 3;      // shared XOR swizzle for all row&7==l15&7 reads
  const float SCL = 0.125f * 1.44269504f;   // score scale in log2 domain

  bf16x8 qf[2][2];
  #pragma unroll
  for (int g = 0; g < 2; g++) {
    const unsigned short* qrow =
        Qg + (size_t)(b * SEQ + q0 + g * 64 + wv * 16 + l15) * D_MODEL + h * DK;
    qf[g][0] = *(const bf16x8*)(qrow + quad * 8);
    qf[g][1] = *(const bf16x8*)(qrow + 32 + quad * 8);
  }
  f32x4 oacc[2][4] = {};
  float m_run[2] = { -1e30f, -1e30f };
  float l_run[2] = { 0.0f, 0.0f };

  // hoisted staging pointers: thread t covers rows (t>>3) and (t>>3)+32,
  // byte-col ((t&7)*8)^swizzle — same swizzle both halves ((row+32)&7 == row&7).
  const int srow = t >> 3;
  const int scol = ((t & 7) * 8) ^ ((srow & 7) << 3);
  const unsigned short* kp = Kg + (size_t)(b * SEQ + srow) * D_MODEL + h * DK + scol;
  const unsigned short* vp = Vt + ((size_t)(b * NH + h) * DK + srow) * SEQ + scol;
  const int* mp = mask + b * SEQ;
  const int prow = wv * 16 + l15;

  for (int kt = 0; kt < SEQ; kt += AKT) {
    gl_lds16(kp,                  &Ks[t * 8]);
    gl_lds16(kp + 32 * D_MODEL,   &Ks[(256 + t) * 8]);
    gl_lds16(vp,                  &Vs[t * 8]);
    gl_lds16(vp + 32 * SEQ,       &Vs[(256 + t) * 8]);
    if (t < AKT) maddf[t] = mp[t] ? 0.0f : -1.0e9f;
    __syncthreads();

    // ---- P1: QK^T both groups, shared K frags; scores in log2 domain ----
    f32x4 sc[2][4];
    #pragma unroll
    for (int ct = 0; ct < 4; ct++) {
      const int krow = ct * 16 + l15;
      bf16x8 kb0 = *(const bf16x8*)&Ks[krow * 64 + ((quad * 8) ^ sw)];
      bf16x8 kb1 = *(const bf16x8*)&Ks[krow * 64 + ((32 + quad * 8) ^ sw)];
      f32x4 a0 = {}, a1 = {};
      a0 = __builtin_amdgcn_mfma_f32_16x16x32_bf16(kb0, qf[0][0], a0, 0, 0, 0);
      a0 = __builtin_amdgcn_mfma_f32_16x16x32_bf16(kb1, qf[0][1], a0, 0, 0, 0);
      a1 = __builtin_amdgcn_mfma_f32_16x16x32_bf16(kb0, qf[1][0], a1, 0, 0, 0);
      a1 = __builtin_amdgcn_mfma_f32_16x16x32_bf16(kb1, qf[1][1], a1, 0, 0, 0);
      f32x4 md = *(const f32x4*)&maddf[ct * 16 + quad * 4];
      #pragma unroll
      for (int r = 0; r < 4; r++) {
        a0[r] = a0[r] * SCL + md[r];
        a1[r] = a1[r] * SCL + md[r];
      }
      sc[0][ct] = a0; sc[1][ct] = a1;
    }

    // ---- P2: softmax per group into its OWN P buffer ----
    #pragma unroll
    for (int g = 0; g < 2; g++) {
      short* Pg = g ? Ps1 : Ps0;
      float tmax = fmaxf(fmaxf(sc[g][0][0], sc[g][0][1]), fmaxf(sc[g][0][2], sc[g][0][3]));
      #pragma unroll
      for (int ct = 1; ct < 4; ct++)
        tmax = fmaxf(tmax, fmaxf(fmaxf(sc[g][ct][0], sc[g][ct][1]),
                                 fmaxf(sc[g][ct][2], sc[g][ct][3])));
      tmax = fmaxf(tmax, __shfl_xor(tmax, 16));
      tmax = fmaxf(tmax, __shfl_xor(tmax, 32));

      // defer-max (T13): only rescale when max grew by > 8 nats (11.54 in log2)
      if (!__all(tmax - m_run[g] <= 11.5415603f)) {
        float mn = fmaxf(m_run[g], tmax);
        float alpha = fexp2(m_run[g] - mn);
        m_run[g] = mn;
        l_run[g] *= alpha;
        float a4[4];
        #pragma unroll
        for (int r = 0; r < 4; r++) a4[r] = __shfl(alpha, quad * 4 + r);
        #pragma unroll
        for (int dt = 0; dt < 4; dt++)
          #pragma unroll
          for (int r = 0; r < 4; r++) oacc[g][dt][r] *= a4[r];
      }

      // P = 2^(S - m); packed bf16 store: 4x ds_write_b64 (P[q][kv], swizzled)
      float rs = 0.0f;
      #pragma unroll
      for (int ct = 0; ct < 4; ct++) {
        float p0 = fexp2(sc[g][ct][0] - m_run[g]);
        float p1 = fexp2(sc[g][ct][1] - m_run[g]);
        float p2 = fexp2(sc[g][ct][2] - m_run[g]);
        float p3 = fexp2(sc[g][ct][3] - m_run[g]);
        rs += (p0 + p1) + (p2 + p3);
        unsigned int lo, hi;
        asm("v_cvt_pk_bf16_f32 %0, %1, %2" : "=v"(lo) : "v"(p0), "v"(p1));
        asm("v_cvt_pk_bf16_f32 %0, %1, %2" : "=v"(hi) : "v"(p2), "v"(p3));
        int2 pv; pv.x = (int)lo; pv.y = (int)hi;
        *(int2*)&Pg[prow * 64 + ((ct * 16 + quad * 4) ^ sw)] = pv;
      }
      rs += __shfl_xor(rs, 16);
      rs += __shfl_xor(rs, 32);
      l_run[g] += rs;
    }

    // ---- P3: PV both groups, shared V frags ----
    bf16x8 pf00 = *(const bf16x8*)&Ps0[prow * 64 + ((quad * 8) ^ sw)];
    bf16x8 pf01 = *(const bf16x8*)&Ps0[prow * 64 + ((32 + quad * 8) ^ sw)];
    bf16x8 pf10 = *(const bf16x8*)&Ps1[prow * 64 + ((quad * 8) ^ sw)];
    bf16x8 pf11 = *(const bf16x8*)&Ps1[prow * 64 + ((32 + quad * 8) ^ sw)];
    #pragma unroll
    for (int dt = 0; dt < 4; dt++) {
      const int vrow = dt * 16 + l15;
      bf16x8 vb0 = *(const bf16x8*)&Vs[vrow * 64 + ((quad * 8) ^ sw)];
      bf16x8 vb1 = *(const bf16x8*)&Vs[vrow * 64 + ((32 + quad * 8) ^ sw)];
      oacc[0][dt] = __builtin_amdgcn_mfma_f32_16x16x32_bf16(pf00, vb0, oacc[0][dt], 0, 0, 0);
      oacc[0][dt] = __builtin_amdgcn_mfma_f32_16x16x32_bf16(pf01, vb1, oacc[0][dt], 0, 0, 0);
      oacc[1][dt] = __builtin_amdgcn_mfma_f32_16x16x32_bf16(pf10, vb0, oacc[1][dt], 0, 0, 0);
      oacc[1][dt] = __builtin_amdgcn_mfma_f32_16x16x32_bf16(pf11, vb1, oacc[1][dt], 0, 0, 0);
    }
    __syncthreads();
    kp += (size_t)AKT * D_MODEL; vp += AKT; mp += AKT;
  }

  // transport 1/l from lane-layout (q=l15) to C-layout (q=quad*4+r)
  #pragma unroll
  for (int g = 0; g < 2; g++) {
    float li = 1.0f / l_run[g];
    float linv4[4];
    #pragma unroll
    for (int r = 0; r < 4; r++) linv4[r] = __shfl(li, quad * 4 + r);
    #pragma unroll
    for (int dt = 0; dt < 4; dt++)
      #pragma unroll
      for (int r = 0; r < 4; r++)
        Og[(size_t)(b * SEQ + q0 + g * 64 + wv * 16 + quad * 4 + r) * D_MODEL + h * DK + dt * 16 + l15] =
          f2bf(oacc[g][dt][r] * linv4[r]);
  }
}

// ---------------- launch ----------------
// fp32 I/O. All GEMMs bf16 with just-in-time weight conversion. NO ws_size gate.
// ws high-water 48MB:
//   phase A: q [0,16)  k [16,32)  vt [32,48)
//   phase B (after attn): ao=q, wo16 -> [16,18) (k dead)
//   phase C (after o-proj): w1 -> [0,8), w2 -> [8,16) (ao dead); ln2 -> [32,48)
//            hff chunk -> [16,32)
// d_out as scratch: ln1b [0,16MB), wqkv16 [16,22MB); o-proj overwrites all with x1 fp32.
extern "C" void kernel_launch(void* const* d_in, const int* in_sizes, int n_in,
                              void* d_out, int out_size, void* d_ws, size_t ws_size,
                              hipStream_t stream)
{
  (void)in_sizes; (void)n_in; (void)out_size; (void)ws_size;
  const float* x   = (const float*)d_in[0];
  const int*   msk = (const int*)d_in[1];
  const float* w_q = (const float*)d_in[2];
  const float* w_k = (const float*)d_in[3];
  const float* w_v = (const float*)d_in[4];
  const float* w_o = (const float*)d_in[5];
  const float* w1  = (const float*)d_in[6];
  const float* b1  = (const float*)d_in[7];
  const float* w2  = (const float*)d_in[8];
  const float* b2  = (const float*)d_in[9];
  const float* g1  = (const float*)d_in[10];
  const float* be1 = (const float*)d_in[11];
  const float* g2  = (const float*)d_in[12];
  const float* be2 = (const float*)d_in[13];
  float* outf = (float*)d_out;

  char* ws = (char*)d_ws;
  const size_t MB = 1024 * 1024;
  unsigned short* q_b  = (unsigned short*)(ws + 0);        // 16MB -> ao
  unsigned short* k_b  = (unsigned short*)(ws + 16 * MB);  // 16MB -> wo16 -> hff chunk
  unsigned short* vt_b = (unsigned short*)(ws + 32 * MB);  // 16MB -> ln2b
  unsigned short* wo16 = (unsigned short*)(ws + 16 * MB);  // 2MB (k dead after attn)
  unsigned short* w116 = (unsigned short*)(ws + 0);        // 8MB (ao dead after o-proj)
  unsigned short* w216 = (unsigned short*)(ws + 8 * MB);   // 8MB
  unsigned short* ln2b = vt_b;                             // 16MB (vt dead after attn)
  unsigned short* hffc = k_b;                              // 16MB chunk

  unsigned short* ln1b   = (unsigned short*)d_out;                  // [0,16MB) of d_out
  unsigned short* wqkv16 = (unsigned short*)d_out + 8 * 1024 * 1024;// [16,22MB) of d_out

  dim3 blk(256);
  const int nw = D_MODEL * D_MODEL;  // 1M elems
  const int nf = DFF * D_MODEL;      // 4M elems

  // phase A: weights q|k|v -> fused bf16 [3072,1024] in d_out scratch; LN1
  cvt_f2b<<<nw / 1024, blk, 0, stream>>>(w_q, wqkv16, nw);
  cvt_f2b<<<nw / 1024, blk, 0, stream>>>(w_k, wqkv16 + nw, nw);
  cvt_f2b<<<nw / 1024, blk, 0, stream>>>(w_v, wqkv16 + 2 * nw, nw);
  ln_kernel<<<NROWS, blk, 0, stream>>>(x, g1, be1, ln1b);

  // fused QKV: [8192,1024] x [3072,1024]^T -> q, k, vt  (1536 blocks, %8==0)
  dim3 gqkv(3 * D_MODEL / 128, NROWS / 128);  // (24, 64)
  gemm_bt<<<gqkv, blk, 0, stream>>>(ln1b, wqkv16, D_MODEL, 3 * D_MODEL, D_MODEL, D_MODEL,
                                    nullptr, 0, nullptr, nullptr, nullptr, nullptr,
                                    q_b, k_b, vt_b);

  // attention (output in-place over q); AQT=128 -> 1024 blocks (%8==0)
  attn_mfma<<<BATCH * NH * (SEQ / AQT), blk, 0, stream>>>(q_b, k_b, vt_b, msk, q_b);

  // phase B: wo -> dead k region; o-proj + residual(x) -> x1 = d_out (fp32)
  cvt_f2b<<<nw / 1024, blk, 0, stream>>>(w_o, wo16, nw);
  dim3 gN1024(D_MODEL / 128, NROWS / 128);  // (8, 64) = 512 blocks
  gemm_bt<<<gN1024, blk, 0, stream>>>(q_b, wo16, D_MODEL, D_MODEL, D_MODEL, D_MODEL,
                                      nullptr, 0, x, nullptr, outf, nullptr,
                                      nullptr, nullptr, nullptr);

  // phase C: w1/w2 -> dead ao region; LN2 -> dead vt region; chunked FFN
  cvt_f2b<<<nf / 1024, blk, 0, stream>>>(w1, w116, nf);
  cvt_f2b<<<nf / 1024, blk, 0, stream>>>(w2, w216, nf);
  ln_kernel<<<NROWS, blk, 0, stream>>>(outf, g2, be2, ln2b);
  for (int c = 0; c < NCHUNK; c++) {
    const size_t ro = (size_t)c * CHUNK;
    dim3 g1c(DFF / 128,     CHUNK / 128);      // (32, 16) = 512 blocks
    dim3 g2c(D_MODEL / 128, CHUNK / 128, 4);   // (8, 16, 4): xy=128 blocks, split-K
    gemm_bt<<<g1c, blk, 0, stream>>>(ln2b + ro * D_MODEL, w116, D_MODEL, DFF,
                                     D_MODEL, D_MODEL, b1, 1,
                                     nullptr, hffc, nullptr, nullptr,
                                     nullptr, nullptr, nullptr);
    // FFN2 split-K=4 (K=1024 each): outf already holds x1 (residual) in place;
    // partials accumulate via device-scope fp32 atomics, bias from split 0.
    gemm_bt<<<g2c, blk, 0, stream>>>(hffc, w216, DFF / 4, D_MODEL, DFF, DFF, b2, 0,
                                     nullptr, nullptr, nullptr, outf + ro * D_MODEL,
                                     nullptr, nullptr, nullptr);
  }
}